// Round 10
// baseline (360.324 us; speedup 1.0000x reference)
//
#include <hip/hip_runtime.h>
#include <hip/hip_bf16.h>

#define EPS 1e-5f

typedef __attribute__((ext_vector_type(8))) short bf16x8;
typedef __attribute__((ext_vector_type(4))) float f32x4;
typedef __attribute__((ext_vector_type(4))) unsigned short u16x4;
typedef __attribute__((ext_vector_type(8))) unsigned short u16x8;

#define WAITVM8 asm volatile("s_waitcnt vmcnt(8)" ::: "memory")
#define WAITVM6 asm volatile("s_waitcnt vmcnt(6)" ::: "memory")
#define WAITVM4 asm volatile("s_waitcnt vmcnt(4)" ::: "memory")
#define WAITVM0 asm volatile("s_waitcnt vmcnt(0)" ::: "memory")
#define LGKM0   asm volatile("s_waitcnt lgkmcnt(0)" ::: "memory")
#define SCHED0  __builtin_amdgcn_sched_barrier(0)
#define BAR()   __builtin_amdgcn_s_barrier()

// ---- async global->LDS, 16B per lane, linear dest (wave-uniform base + lane*16)
__device__ __forceinline__ void gld_lds16(const void* g, void* l) {
    __builtin_amdgcn_global_load_lds(
        (const __attribute__((address_space(1))) unsigned int*)g,
        (__attribute__((address_space(3))) unsigned int*)l, 16, 0, 0);
}

// ---- macros shared with head1 (R9 structure, unchanged there)
#define RD8(RA, RB, SEL) do {                                                  \
    const int _b = (SEL) * 8192;                                               \
    _Pragma("unroll") for (int _i = 0; _i < 4; ++_i)                           \
        RA[_i] = *reinterpret_cast<const bf16x8*>(&lA[_b + aoff + _i * 512]);  \
    _Pragma("unroll") for (int _j = 0; _j < 4; ++_j)                           \
        RB[_j] = *reinterpret_cast<const bf16x8*>(&lB[_b + boff + _j * 512]);  \
} while (0)

#define RD4(RA4, SEL) do {                                                     \
    const int _b = (SEL) * 8192;                                               \
    _Pragma("unroll") for (int _i = 0; _i < 4; ++_i)                           \
        RA4[_i] = *reinterpret_cast<const bf16x8*>(                            \
            &lA[_b + aoff + (_i + 4) * 512]);                                  \
} while (0)

#define MFQ(RA, RB, I0) do {                                                   \
    _Pragma("unroll") for (int _i = 0; _i < 4; ++_i)                           \
    _Pragma("unroll") for (int _j = 0; _j < 4; ++_j)                           \
        acc[(I0) + _i][_j] = __builtin_amdgcn_mfma_f32_16x16x32_bf16(          \
            RA[_i], RB[_j], acc[(I0) + _i][_j], 0, 0, 0);                      \
} while (0)

#define STEP(CA0, CA4, CB, NA0, NB, SELT, STAGE_STMT, WAIT_STMT, DORD) do {    \
    RD4(CA4, (SELT));                                                          \
    STAGE_STMT;                                                                \
    __builtin_amdgcn_s_setprio(1); MFQ(CA0, CB, 0);                            \
    __builtin_amdgcn_s_setprio(0);                                             \
    WAIT_STMT;                                                                 \
    BAR();                                                                     \
    if (DORD) RD8(NA0, NB, ((SELT) + 1) & 3);                                  \
    __builtin_amdgcn_s_setprio(1); MFQ(CA4, CB, 4);                            \
    __builtin_amdgcn_s_setprio(0);                                             \
} while (0)

// ---- m201-style phase pair for one K32 unit (conv_search kernel).
// Phase A: read B[0..3]+A[0..3], issue A-stage(u+3), BAR, lgkm0, 16 MFMA, BAR.
// Phase B: read A[4..7], issue B-stage(u+3), counted vmcnt, BAR, lgkm0,
//          16 MFMA, BAR.  B-frags register-resident across both phases.
#define UNIT(SEL, SA_STMT, SB_STMT, WAIT_STMT) do {                            \
    { const int _b = (SEL) * 8192;                                             \
      _Pragma("unroll") for (int _j = 0; _j < 4; ++_j)                         \
        Bf[_j] = *reinterpret_cast<const bf16x8*>(&lB[_b + boff + _j * 512]);  \
      _Pragma("unroll") for (int _i = 0; _i < 4; ++_i)                         \
        A0[_i] = *reinterpret_cast<const bf16x8*>(&lA[_b + aoff + _i * 512]); }\
    SA_STMT;                                                                   \
    BAR(); LGKM0; SCHED0;                                                      \
    __builtin_amdgcn_s_setprio(1); MFQ(A0, Bf, 0);                             \
    __builtin_amdgcn_s_setprio(0);                                             \
    BAR();                                                                     \
    { const int _b = (SEL) * 8192;                                             \
      _Pragma("unroll") for (int _i = 0; _i < 4; ++_i)                         \
        A4[_i] = *reinterpret_cast<const bf16x8*>(                             \
            &lA[_b + aoff + (_i + 4) * 512]); }                                \
    SB_STMT;                                                                   \
    WAIT_STMT;                                                                 \
    BAR(); LGKM0; SCHED0;                                                      \
    __builtin_amdgcn_s_setprio(1); MFQ(A4, Bf, 4);                             \
    __builtin_amdgcn_s_setprio(0);                                             \
    BAR();                                                                     \
} while (0)

// ---------------- pre-pass: weights [256][256][3][3] f32 -> [256][9][256] bf16
__global__ __launch_bounds__(256) void wt_transpose_bf16(
    const float* __restrict__ w, __hip_bfloat16* __restrict__ wt)
{
    const int co = blockIdx.x;
    const int ci = threadIdx.x;
    const float* wp = w + (size_t)co * 2304 + (size_t)ci * 9;
    __hip_bfloat16* wo = wt + (size_t)co * 2304 + ci;
#pragma unroll
    for (int j = 0; j < 9; ++j)
        wo[(size_t)j * 256] = __float2bfloat16(wp[j]);
}

// ---------------- pre-pass: f32 -> bf16 elementwise (for w_h1)
__global__ __launch_bounds__(256) void f32_to_bf16(
    const float* __restrict__ x, __hip_bfloat16* __restrict__ y, int n)
{
    int i = blockIdx.x * 256 + threadIdx.x;
    if (i < n) y[i] = __float2bfloat16(x[i]);
}

// ---------------- pre-pass v2: x [B][256][P] f32 -> xt [B][P][256] bf16
__global__ __launch_bounds__(256) void nchw_to_nhwc_v2(
    const float* __restrict__ x, __hip_bfloat16* __restrict__ xt, int P)
{
    const int b  = blockIdx.y;
    const int p0 = blockIdx.x * 32;
    __shared__ float t[256][33];
    const float* xb = x + (size_t)b * 256 * P;
    const int pl = threadIdx.x & 31, cg = threadIdx.x >> 5;
#pragma unroll
    for (int it = 0; it < 32; ++it) {
        int c = cg + it * 8, p = p0 + pl;
        t[c][pl] = (p < P) ? xb[(size_t)c * P + p] : 0.f;
    }
    __syncthreads();
    const int p = threadIdx.x >> 3, l8 = threadIdx.x & 7;
    if (p0 + p < P) {
        __hip_bfloat16* xo = xt + ((size_t)b * P + p0 + p) * 256;
#pragma unroll
        for (int j = 0; j < 4; ++j) {
            const int c0 = j * 64 + l8 * 8;
            u16x8 o;
#pragma unroll
            for (int r = 0; r < 8; ++r) {
                __hip_bfloat16 hv = __float2bfloat16(t[c0 + r][p]);
                o[r] = *reinterpret_cast<unsigned short*>(&hv);
            }
            *reinterpret_cast<u16x8*>(&xo[c0]) = o;
        }
    }
}

// ---------------- conv3x3 search-branch: 8-wave, m201 phase schedule ---------
// M=256 (full), N-tile=256 px, K=2304 (72 K32 units, 2 phases each).
// 512 thr = 8 waves (2M x 4N), per-wave 128x64. 4 LDS buffers (128 KB),
// depth-3 staging, vmcnt(8) once per unit, lgkmcnt(0)+sched_barrier(0) per
// phase, setprio around each 16-MFMA cluster, slot-swizzled LDS.
template<int HIN, int WIN, int NTOT>
__global__ __launch_bounds__(512, 2) void conv3x3_mfma8(
    const __hip_bfloat16* __restrict__ xt,  // [B][HIN][WIN][256]
    const __hip_bfloat16* __restrict__ wt,  // [256][9][256]
    const float* __restrict__ g, const float* __restrict__ bb,
    const float* __restrict__ mm_, const float* __restrict__ vv,
    __hip_bfloat16* __restrict__ y)         // NHWC: [NTOT][256]
{
    constexpr int HOUT = HIN - 2, WOUT = WIN - 2, POUT = HOUT * WOUT;
    const int n0  = blockIdx.x * 256;
    const int tid = threadIdx.x;
    const int wid = tid >> 6, lane = tid & 63;
    const int wr = wid >> 2, wc = wid & 3;

    __shared__ __align__(16) __hip_bfloat16 lA[4 * 8192];  // 4 bufs of [256][32]
    __shared__ __align__(16) __hip_bfloat16 lB[4 * 8192];

    const int arow = tid >> 2;                       // 0..127
    const int seg  = (tid & 3) ^ ((tid >> 3) & 3);   // inverse slot-swizzle

    const size_t wbase0 = (size_t)arow * 2304 + seg * 8;
    const size_t wbase1 = (size_t)(arow + 128) * 2304 + seg * 8;

    int nr0 = n0 + arow;       if (nr0 > NTOT - 1) nr0 = NTOT - 1;
    int nr1 = n0 + arow + 128; if (nr1 > NTOT - 1) nr1 = NTOT - 1;
    int b0 = nr0 / POUT, p0 = nr0 % POUT, oy0 = p0 / WOUT, ox0 = p0 % WOUT;
    int b1 = nr1 / POUT, p1 = nr1 % POUT, oy1 = p1 / WOUT, ox1 = p1 % WOUT;
    const size_t xbase0 = (((size_t)b0 * HIN + oy0) * WIN + ox0) * 256 + seg * 8;
    const size_t xbase1 = (((size_t)b1 * HIN + oy1) * WIN + ox1) * 256 + seg * 8;

    // A-half / B-half staging of one K32 unit (2 gld each)
    auto stageA = [&](int c0, int j, int sel) {
        char* a0 = (char*)lA + sel * 16384 + wid * 1024;
        const int woff = j * 256 + c0;
        gld_lds16(wt + wbase0 + woff, a0);
        gld_lds16(wt + wbase1 + woff, a0 + 8192);
    };
    auto stageB = [&](int c0, int j, int sel) {
        char* b0p = (char*)lB + sel * 16384 + wid * 1024;
        const int xoff = ((j / 3) * WIN + (j % 3)) * 256 + c0;
        gld_lds16(xt + xbase0 + xoff, b0p);
        gld_lds16(xt + xbase1 + xoff, b0p + 8192);
    };

    f32x4 acc[8][4];
#pragma unroll
    for (int i = 0; i < 8; ++i)
#pragma unroll
        for (int j = 0; j < 4; ++j)
            acc[i][j] = f32x4{0.f, 0.f, 0.f, 0.f};

    const int l15 = lane & 15, l16 = lane >> 4;
    const int slot = l16 ^ ((l15 >> 1) & 3);
    const int aoff = (wr * 128 + l15) * 32 + slot * 8;
    const int boff = (wc * 64  + l15) * 32 + slot * 8;

    bf16x8 A0[4], A4[4], Bf[4];

    // prologue: fully stage units 0,1,2 in unit order (12 gld in flight)
    stageA(0, 0, 0); stageB(0, 0, 0);
    stageA(0, 1, 1); stageB(0, 1, 1);
    stageA(0, 2, 2); stageB(0, 2, 2);
    int js = 3, c0s = 0;  // cursor for unit u+3
    WAITVM8;              // unit 0 resident; units 1,2 in flight
    BAR();

#define ADV do { ++js; if (js == 9) { js = 0; c0s += 32; } } while (0)
    // main loop: units u = 0..67
    for (int tt = 0; tt < 17; ++tt) {
        UNIT(0, stageA(c0s, js, 3), stageB(c0s, js, 3), WAITVM8); ADV;
        UNIT(1, stageA(c0s, js, 0), stageB(c0s, js, 0), WAITVM8); ADV;
        UNIT(2, stageA(c0s, js, 1), stageB(c0s, js, 1), WAITVM8); ADV;
        UNIT(3, stageA(c0s, js, 2), stageB(c0s, js, 2), WAITVM8); ADV;
    }
    // tail: u = 68 (stages unit 71), 69, 70, 71
    UNIT(0, stageA(c0s, js, 3), stageB(c0s, js, 3), WAITVM8);
    UNIT(1, (void)0, (void)0, WAITVM4);
    UNIT(2, (void)0, (void)0, WAITVM0);
    UNIT(3, (void)0, (void)0, (void)0);
#undef ADV

    // epilogue: co = wr*128 + i*16 + l16*4 + r; n = n0 + wc*64 + jj*16 + l15
#pragma unroll
    for (int i = 0; i < 8; ++i) {
        const int co_b = wr * 128 + i * 16 + l16 * 4;
        float sc[4], sh[4];
#pragma unroll
        for (int r = 0; r < 4; ++r) {
            sc[r] = g[co_b + r] * rsqrtf(vv[co_b + r] + EPS);
            sh[r] = bb[co_b + r] - mm_[co_b + r] * sc[r];
        }
#pragma unroll
        for (int jj = 0; jj < 4; ++jj) {
            const int n = n0 + wc * 64 + jj * 16 + l15;
            if (n < NTOT) {
                u16x4 o;
#pragma unroll
                for (int r = 0; r < 4; ++r) {
                    const float v = fmaxf(fmaf(acc[i][jj][r], sc[r], sh[r]), 0.f);
                    __hip_bfloat16 hv = __float2bfloat16(v);
                    o[r] = *reinterpret_cast<unsigned short*>(&hv);
                }
                *reinterpret_cast<u16x4*>(&y[(size_t)n * 256 + co_b]) = o;
            }
        }
    }
}

// ---------------- conv3x3 kernel-branch: split-K partial ----------------
__global__ __launch_bounds__(256, 2) void conv3x3_partial(
    const __hip_bfloat16* __restrict__ xt,  // [B][7][7][256]
    const __hip_bfloat16* __restrict__ wt,  // [256][9][256]
    float* __restrict__ part)               // [4][3200][256]
{
    constexpr int HIN = 7, WIN = 7, POUT = 25;
    const int n0  = blockIdx.x * 128;
    const int kc0 = blockIdx.y * 64;
    const int kidx = blockIdx.y;
    const int tid = threadIdx.x;
    const int wid = tid >> 6, lane = tid & 63;
    const int wr = wid >> 1, wc = wid & 1;

    __shared__ __align__(16) __hip_bfloat16 sA[3 * 8192];
    __shared__ __align__(16) __hip_bfloat16 sB[3 * 4096];

    const int srow = wid * 16 + (lane >> 2);
    const int seg  = (lane & 3) ^ ((lane >> 3) & 3);

    const size_t wbase = (size_t)srow * 2304 + seg * 8;
    int nr0 = n0 + srow;
    int b0 = nr0 / POUT, p0 = nr0 % POUT, oy0 = p0 / 5, ox0 = p0 % 5;
    const size_t xbase0 = (((size_t)b0 * HIN + oy0) * WIN + ox0) * 256 + seg * 8;
    int nr1 = nr0 + 64;
    int b1 = nr1 / POUT, p1 = nr1 % POUT, oy1 = p1 / 5, ox1 = p1 % 5;
    const size_t xbase1 = (((size_t)b1 * HIN + oy1) * WIN + ox1) * 256 + seg * 8;

    auto stage = [&](int c0, int j, int sel) {
        char* a0 = (char*)sA + sel * 16384 + wid * 1024;
        char* b0p = (char*)sB + sel * 8192 + wid * 1024;
        const int woff = j * 256 + c0;
        gld_lds16(wt + wbase + woff,              a0);
        gld_lds16(wt + wbase + 64 * 2304 + woff,  a0 + 4096);
        gld_lds16(wt + wbase + 128 * 2304 + woff, a0 + 8192);
        gld_lds16(wt + wbase + 192 * 2304 + woff, a0 + 12288);
        const int xoff = ((j / 3) * WIN + (j % 3)) * 256 + c0;
        gld_lds16(xt + xbase0 + xoff, b0p);
        gld_lds16(xt + xbase1 + xoff, b0p + 4096);
    };

    f32x4 acc[8][4];
#pragma unroll
    for (int i = 0; i < 8; ++i)
#pragma unroll
        for (int j = 0; j < 4; ++j)
            acc[i][j] = f32x4{0.f, 0.f, 0.f, 0.f};

    const int l15 = lane & 15, l16 = lane >> 4;
    const int slot = l16 ^ ((l15 >> 1) & 3);
    const int aoffp = (wr * 128 + l15) * 32 + slot * 8;
    const int boffp = (wc * 64  + l15) * 32 + slot * 8;

    auto compute = [&](int sel) {
        const int ab = sel * 8192, bb_ = sel * 4096;
        bf16x8 b[4];
#pragma unroll
        for (int j = 0; j < 4; ++j)
            b[j] = *reinterpret_cast<const bf16x8*>(&sB[bb_ + boffp + j * 512]);
#pragma unroll
        for (int i = 0; i < 8; ++i) {
            bf16x8 a = *reinterpret_cast<const bf16x8*>(&sA[ab + aoffp + i * 512]);
#pragma unroll
            for (int j = 0; j < 4; ++j)
                acc[i][j] = __builtin_amdgcn_mfma_f32_16x16x32_bf16(
                    a, b[j], acc[i][j], 0, 0, 0);
        }
    };

    stage(kc0, 0, 0); stage(kc0, 1, 1);
    int js = 2, c0s = kc0;
    for (int t = 0; t < 16; ++t) {
        WAITVM6; BAR();
        stage(c0s, js, (t + 2) % 3);
        ++js; if (js == 9) { js = 0; c0s += 32; }
        compute(t % 3);
    }
    WAITVM6; BAR(); compute(16 % 3);
    WAITVM0; BAR(); compute(17 % 3);

#pragma unroll
    for (int i = 0; i < 8; ++i) {
        const int co_b = wr * 128 + i * 16 + l16 * 4;
#pragma unroll
        for (int jj = 0; jj < 4; ++jj) {
            const int n = n0 + wc * 64 + jj * 16 + l15;
            f32x4 o = acc[i][jj];
            *reinterpret_cast<f32x4*>(
                &part[((size_t)kidx * 3200 + n) * 256 + co_b]) = o;
        }
    }
}

// ---------------- reduce split-K partials + BN + ReLU -> y1 bf16
__global__ __launch_bounds__(256) void reduce_bn_relu(
    const float* __restrict__ part,  // [4][3200][256]
    const float* __restrict__ g, const float* __restrict__ bb,
    const float* __restrict__ mm_, const float* __restrict__ vv,
    __hip_bfloat16* __restrict__ y1) // [3200][256]
{
    const int n = blockIdx.x, co = threadIdx.x;
    float s = part[(size_t)n * 256 + co]
            + part[((size_t)3200 + n) * 256 + co]
            + part[((size_t)6400 + n) * 256 + co]
            + part[((size_t)9600 + n) * 256 + co];
    const float sc = g[co] * rsqrtf(vv[co] + EPS);
    const float sh = bb[co] - mm_[co] * sc;
    y1[(size_t)n * 256 + co] = __float2bfloat16(fmaxf(fmaf(s, sc, sh), 0.f));
}

// ---------------- depthwise xcorr 5x5, NHWC, bf16x2 vectorized ----------------
__global__ __launch_bounds__(128) void xcorr_dw_nhwc2(
    const __hip_bfloat16* __restrict__ s,  // [B][841][256]
    const __hip_bfloat16* __restrict__ k,  // [B][25][256]
    __hip_bfloat16* __restrict__ f)        // [B][625][256]
{
    const int py = blockIdx.x, b = blockIdx.y, c2 = threadIdx.x;  // ch pair
    const ushort2* sp = reinterpret_cast<const ushort2*>(s + (size_t)b * 841 * 256) + c2;
    const ushort2* kp = reinterpret_cast<const ushort2*>(k + (size_t)b * 25 * 256) + c2;

    float a0[25], a1[25];
#pragma unroll
    for (int i = 0; i < 25; ++i) { a0[i] = 0.f; a1[i] = 0.f; }

    for (int ky = 0; ky < 5; ++ky) {
        const ushort2* srp = sp + (size_t)(py + ky) * 29 * 128;
        float s0[29], s1[29];
#pragma unroll
        for (int rx = 0; rx < 29; ++rx) {
            ushort2 u = srp[(size_t)rx * 128];
            unsigned int w0 = (unsigned int)u.x << 16, w1 = (unsigned int)u.y << 16;
            s0[rx] = *reinterpret_cast<float*>(&w0);
            s1[rx] = *reinterpret_cast<float*>(&w1);
        }
#pragma unroll
        for (int kx = 0; kx < 5; ++kx) {
            ushort2 u = kp[(size_t)(ky * 5 + kx) * 128];
            unsigned int w0 = (unsigned int)u.x << 16, w1 = (unsigned int)u.y << 16;
            const float k0 = *reinterpret_cast<float*>(&w0);
            const float k1 = *reinterpret_cast<float*>(&w1);
#pragma unroll
            for (int px = 0; px < 25; ++px) {
                a0[px] = fmaf(s0[px + kx], k0, a0[px]);
                a1[px] = fmaf(s1[px + kx], k1, a1[px]);
            }
        }
    }

    ushort2* fp = reinterpret_cast<ushort2*>(f + ((size_t)b * 625 + (size_t)py * 25) * 256) + c2;
#pragma unroll
    for (int px = 0; px < 25; ++px) {
        __hip_bfloat16 h0 = __float2bfloat16(a0[px]);
        __hip_bfloat16 h1 = __float2bfloat16(a1[px]);
        ushort2 o;
        o.x = *reinterpret_cast<unsigned short*>(&h0);
        o.y = *reinterpret_cast<unsigned short*>(&h1);
        fp[(size_t)px * 128] = o;
    }
}

// ---------------- head layer 1: 1x1 conv, 8-wave pipelined (R9 structure) ----
__global__ __launch_bounds__(512, 2) void head1_mfma8(
    const __hip_bfloat16* __restrict__ f,   // [N][256]
    const __hip_bfloat16* __restrict__ w1,  // [256][256] bf16
    const float* __restrict__ g, const float* __restrict__ bb,
    const float* __restrict__ mm_, const float* __restrict__ vv,
    __hip_bfloat16* __restrict__ h)         // [N][256]
{
    constexpr int NTOT = 80000;
    const int n0  = blockIdx.x * 256;
    const int tid = threadIdx.x;
    const int wid = tid >> 6, lane = tid & 63;
    const int wr = wid >> 2, wc = wid & 3;

    __shared__ __align__(16) __hip_bfloat16 lA[4 * 8192];
    __shared__ __align__(16) __hip_bfloat16 lB[4 * 8192];

    const int arow = tid >> 2;
    const int seg  = (tid & 3) ^ ((tid >> 3) & 3);

    const size_t wbase0 = (size_t)arow * 256 + seg * 8;
    const size_t wbase1 = (size_t)(arow + 128) * 256 + seg * 8;
    int nr0 = n0 + arow;       if (nr0 > NTOT - 1) nr0 = NTOT - 1;
    int nr1 = n0 + arow + 128; if (nr1 > NTOT - 1) nr1 = NTOT - 1;
    const size_t xbase0 = (size_t)nr0 * 256 + seg * 8;
    const size_t xbase1 = (size_t)nr1 * 256 + seg * 8;

    auto stage = [&](int c0, int sel) {
        char* a0 = (char*)lA + sel * 16384 + wid * 1024;
        char* b0p = (char*)lB + sel * 16384 + wid * 1024;
        gld_lds16(w1 + wbase0 + c0, a0);
        gld_lds16(w1 + wbase1 + c0, a0 + 8192);
        gld_lds16(f + xbase0 + c0, b0p);
        gld_lds16(f + xbase1 + c0, b0p + 8192);
    };

    f32x4 acc[8][4];
#pragma unroll
    for (int i = 0; i < 8; ++i)
#pragma unroll
        for (int j = 0; j < 4; ++j)
            acc[i][j] = f32x4{0.f, 0.f, 0.f, 0.f};

    const int l15 = lane & 15, l16 = lane >> 4;
    const int slot = l16 ^ ((l15 >> 1) & 3);
    const int aoff = (wr * 128 + l15) * 32 + slot * 8;
    const int boff = (wc * 64  + l15) * 32 + slot * 8;

    bf16x8 pA0[4], pA4[4], pB[4], qA0[4], qA4[4], qB[4];

    stage(0, 0); stage(32, 1); stage(64, 2);
    WAITVM8; BAR();
    RD8(pA0, pB, 0);

    STEP(pA0, pA4, pB, qA0, qB, 0, stage(96, 3),  WAITVM8, true);   // t=0
    STEP(qA0, qA4, qB, pA0, pB, 1, stage(128, 0), WAITVM8, true);   // t=1
    STEP(pA0, pA4, pB, qA0, qB, 2, stage(160, 1), WAITVM8, true);   // t=2
    STEP(qA0, qA4, qB, pA0, pB, 3, stage(192, 2), WAITVM8, true);   // t=3
    STEP(pA0, pA4, pB, qA0, qB, 0, stage(224, 3), WAITVM8, true);   // t=4
    STEP(qA0, qA4, qB, pA0, pB, 1, (void)0,       WAITVM4, true);   // t=5
    STEP(pA0, pA4, pB, qA0, qB, 2, (void)0,       WAITVM0, true);   // t=6
    STEP(qA0, qA4, qB, pA0, pB, 3, (void)0,       (void)0, false);  // t=7

#pragma unroll
    for (int i = 0; i < 8; ++i) {
        const int co_b = wr * 128 + i * 16 + l16 * 4;
        float sc[4], sh[4];
#pragma unroll
        for (int r = 0; r < 4; ++r) {
            sc[r] = g[co_b + r] * rsqrtf(vv[co_b + r] + EPS);
            sh[r] = bb[co_b + r] - mm_[co_b + r] * sc[r];
        }
#pragma unroll
        for (int jj = 0; jj < 4; ++jj) {
            const int n = n0 + wc * 64 + jj * 16 + l15;
            if (n < NTOT) {
                u16x4 o;
#pragma unroll
                for (int r = 0; r < 4; ++r) {
                    const float v = fmaxf(fmaf(acc[i][jj][r], sc[r], sh[r]), 0.f);
                    __hip_bfloat16 hv = __float2bfloat16(v);
                    o[r] = *reinterpret_cast<unsigned short*>(&hv);
                }
                *reinterpret_cast<u16x4*>(&h[(size_t)n * 256 + co_b]) = o;
            }
        }
    }
}

// ---------------- head layer 2: 1x1 conv (256 -> 10) + bias, NCHW out --------
__global__ __launch_bounds__(256) void head2(
    const __hip_bfloat16* __restrict__ h,  // [N][256]
    const float* __restrict__ w2,          // [10][256]
    const float* __restrict__ b2,          // [10]
    float* __restrict__ out)               // [B][10][25][25]
{
    const int py = blockIdx.x, b = blockIdx.y;
    __shared__ __hip_bfloat16 lh[25][258];
    __shared__ float lw[10][256];

    const __hip_bfloat16* hp = h + ((size_t)b * 625 + (size_t)py * 25) * 256;
    for (int i = threadIdx.x; i < 25 * 256; i += 256) {
        int px = i >> 8, c = i & 255;
        lh[px][c] = hp[i];
    }
    for (int i = threadIdx.x; i < 10 * 256; i += 256)
        lw[i >> 8][i & 255] = w2[i];
    __syncthreads();

    if (threadIdx.x < 250) {
        const int o = threadIdx.x / 25, px = threadIdx.x % 25;
        float a = b2[o];
        for (int c = 0; c < 256; ++c)
            a = fmaf(__bfloat162float(lh[px][c]), lw[o][c], a);
        out[(((size_t)b * 10 + o) * 25 + py) * 25 + px] = a;
    }
}

extern "C" void kernel_launch(void* const* d_in, const int* in_sizes, int n_in,
                              void* d_out, int out_size, void* d_ws, size_t ws_size,
                              hipStream_t stream) {
    const float* kernel = (const float*)d_in[0];   // [128,256,7,7]
    const float* search = (const float*)d_in[1];   // [128,256,31,31]
    const float* w_ck   = (const float*)d_in[2];
    const float* g1 = (const float*)d_in[3];
    const float* b1 = (const float*)d_in[4];
    const float* m1 = (const float*)d_in[5];
    const float* v1 = (const float*)d_in[6];
    const float* w_cs   = (const float*)d_in[7];
    const float* g2 = (const float*)d_in[8];
    const float* b2 = (const float*)d_in[9];
    const float* m2 = (const float*)d_in[10];
    const float* v2 = (const float*)d_in[11];
    const float* w_h1   = (const float*)d_in[12];
    const float* g3 = (const float*)d_in[13];
    const float* b3 = (const float*)d_in[14];
    const float* m3 = (const float*)d_in[15];
    const float* v3 = (const float*)d_in[16];
    const float* w_h2   = (const float*)d_in[17];
    const float* b_h2   = (const float*)d_in[18];

    float* out = (float*)d_out;

    __hip_bfloat16* ws = (__hip_bfloat16*)d_ws;
    __hip_bfloat16* y1    = ws;
    __hip_bfloat16* y2    = ws + (size_t)819200;
    float*          part  = (float*)(ws + (size_t)819200);
    __hip_bfloat16* wt_ck = ws + (size_t)28377088;
    __hip_bfloat16* wt_cs = ws + (size_t)28966912;
    __hip_bfloat16* wh1   = ws + (size_t)29556736;
    __hip_bfloat16* xt_k  = ws + (size_t)29622272;
    __hip_bfloat16* xt_s  = ws + (size_t)31227904;
    __hip_bfloat16* feat  = ws + (size_t)29622272;
    __hip_bfloat16* h     = ws + (size_t)819200;

    (void)in_sizes; (void)n_in; (void)out_size; (void)ws_size;

    // pre-passes
    wt_transpose_bf16<<<256, 256, 0, stream>>>(w_ck, wt_ck);
    wt_transpose_bf16<<<256, 256, 0, stream>>>(w_cs, wt_cs);
    f32_to_bf16<<<256, 256, 0, stream>>>(w_h1, wh1, 65536);
    nchw_to_nhwc_v2<<<dim3(2, 128), 256, 0, stream>>>(kernel, xt_k, 49);
    nchw_to_nhwc_v2<<<dim3(31, 128), 256, 0, stream>>>(search, xt_s, 961);

    // kernel branch: split-K x4 partials (into y2 region) + reduce -> y1
    conv3x3_partial<<<dim3(25, 4), 256, 0, stream>>>(xt_k, wt_ck, part);
    reduce_bn_relu<<<3200, 256, 0, stream>>>(part, g1, b1, m1, v1, y1);

    // search branch: m201-phase implicit GEMM -> y2 (N=107648, 421 tiles)
    conv3x3_mfma8<31, 31, 107648><<<421, 512, 0, stream>>>(
        xt_s, wt_cs, g2, b2, m2, v2, y2);

    // depthwise xcorr -> feat NHWC
    xcorr_dw_nhwc2<<<dim3(25, 128), 128, 0, stream>>>(y2, y1, feat);

    // head
    head1_mfma8<<<313, 512, 0, stream>>>(feat, wh1, g3, b3, m3, v3, h);
    head2<<<dim3(25, 128), 256, 0, stream>>>(h, w_h2, b_h2, out);
}

// Round 11
// 353.629 us; speedup vs baseline: 1.0189x; 1.0189x over previous
//
#include <hip/hip_runtime.h>
#include <hip/hip_bf16.h>

#define EPS 1e-5f

typedef __attribute__((ext_vector_type(8))) short bf16x8;
typedef __attribute__((ext_vector_type(4))) float f32x4;
typedef __attribute__((ext_vector_type(4))) unsigned short u16x4;
typedef __attribute__((ext_vector_type(8))) unsigned short u16x8;

#define WAITVM8 asm volatile("s_waitcnt vmcnt(8)" ::: "memory")
#define WAITVM6 asm volatile("s_waitcnt vmcnt(6)" ::: "memory")
#define WAITVM4 asm volatile("s_waitcnt vmcnt(4)" ::: "memory")
#define WAITVM0 asm volatile("s_waitcnt vmcnt(0)" ::: "memory")
#define BAR()   __builtin_amdgcn_s_barrier()

// ---- async global->LDS, 16B per lane, linear dest (wave-uniform base + lane*16)
__device__ __forceinline__ void gld_lds16(const void* g, void* l) {
    __builtin_amdgcn_global_load_lds(
        (const __attribute__((address_space(1))) unsigned int*)g,
        (__attribute__((address_space(3))) unsigned int*)l, 16, 0, 0);
}

// ---- GEMM step macros (R9 schedule: 1 barrier + 1 counted vm-wait per K32).
#define RD8(RA, RB, SEL) do {                                                  \
    const int _b = (SEL) * 8192;                                               \
    _Pragma("unroll") for (int _i = 0; _i < 4; ++_i)                           \
        RA[_i] = *reinterpret_cast<const bf16x8*>(&lA[_b + aoff + _i * 512]);  \
    _Pragma("unroll") for (int _j = 0; _j < 4; ++_j)                           \
        RB[_j] = *reinterpret_cast<const bf16x8*>(&lB[_b + boff + _j * 512]);  \
} while (0)

#define RD4(RA4, SEL) do {                                                     \
    const int _b = (SEL) * 8192;                                               \
    _Pragma("unroll") for (int _i = 0; _i < 4; ++_i)                           \
        RA4[_i] = *reinterpret_cast<const bf16x8*>(                            \
            &lA[_b + aoff + (_i + 4) * 512]);                                  \
} while (0)

#define MFQ(RA, RB, I0) do {                                                   \
    _Pragma("unroll") for (int _i = 0; _i < 4; ++_i)                           \
    _Pragma("unroll") for (int _j = 0; _j < 4; ++_j)                           \
        acc[(I0) + _i][_j] = __builtin_amdgcn_mfma_f32_16x16x32_bf16(          \
            RA[_i], RB[_j], acc[(I0) + _i][_j], 0, 0, 0);                      \
} while (0)

#define STEP(CA0, CA4, CB, NA0, NB, SELT, STAGE_STMT, WAIT_STMT, DORD) do {    \
    RD4(CA4, (SELT));                                                          \
    STAGE_STMT;                                                                \
    __builtin_amdgcn_s_setprio(1); MFQ(CA0, CB, 0);                            \
    __builtin_amdgcn_s_setprio(0);                                             \
    WAIT_STMT;                                                                 \
    BAR();                                                                     \
    if (DORD) RD8(NA0, NB, ((SELT) + 1) & 3);                                  \
    __builtin_amdgcn_s_setprio(1); MFQ(CA4, CB, 4);                            \
    __builtin_amdgcn_s_setprio(0);                                             \
} while (0)

// ---------------- pre-pass: weights [256][256][3][3] f32 -> [256][9][256] bf16
__global__ __launch_bounds__(256) void wt_transpose_bf16(
    const float* __restrict__ w, __hip_bfloat16* __restrict__ wt)
{
    const int co = blockIdx.x;
    const int ci = threadIdx.x;
    const float* wp = w + (size_t)co * 2304 + (size_t)ci * 9;
    __hip_bfloat16* wo = wt + (size_t)co * 2304 + ci;
#pragma unroll
    for (int j = 0; j < 9; ++j)
        wo[(size_t)j * 256] = __float2bfloat16(wp[j]);
}

// ---------------- pre-pass: f32 -> bf16 elementwise (for w_h1)
__global__ __launch_bounds__(256) void f32_to_bf16(
    const float* __restrict__ x, __hip_bfloat16* __restrict__ y, int n)
{
    int i = blockIdx.x * 256 + threadIdx.x;
    if (i < n) y[i] = __float2bfloat16(x[i]);
}

// ---------------- pre-pass v2: x [B][256][P] f32 -> xt [B][P][256] bf16
__global__ __launch_bounds__(256) void nchw_to_nhwc_v2(
    const float* __restrict__ x, __hip_bfloat16* __restrict__ xt, int P)
{
    const int b  = blockIdx.y;
    const int p0 = blockIdx.x * 32;
    __shared__ float t[256][33];
    const float* xb = x + (size_t)b * 256 * P;
    const int pl = threadIdx.x & 31, cg = threadIdx.x >> 5;
#pragma unroll
    for (int it = 0; it < 32; ++it) {
        int c = cg + it * 8, p = p0 + pl;
        t[c][pl] = (p < P) ? xb[(size_t)c * P + p] : 0.f;
    }
    __syncthreads();
    const int p = threadIdx.x >> 3, l8 = threadIdx.x & 7;
    if (p0 + p < P) {
        __hip_bfloat16* xo = xt + ((size_t)b * P + p0 + p) * 256;
#pragma unroll
        for (int j = 0; j < 4; ++j) {
            const int c0 = j * 64 + l8 * 8;
            u16x8 o;
#pragma unroll
            for (int r = 0; r < 8; ++r) {
                __hip_bfloat16 hv = __float2bfloat16(t[c0 + r][p]);
                o[r] = *reinterpret_cast<unsigned short*>(&hv);
            }
            *reinterpret_cast<u16x8*>(&xo[c0]) = o;
        }
    }
}

// ---------------- conv3x3 search-branch: 8-wave pipelined (R9 schedule) ------
template<int HIN, int WIN, int NTOT>
__global__ __launch_bounds__(512, 2) void conv3x3_mfma8(
    const __hip_bfloat16* __restrict__ xt,  // [B][HIN][WIN][256]
    const __hip_bfloat16* __restrict__ wt,  // [256][9][256]
    const float* __restrict__ g, const float* __restrict__ bb,
    const float* __restrict__ mm_, const float* __restrict__ vv,
    __hip_bfloat16* __restrict__ y)         // NHWC: [NTOT][256]
{
    constexpr int HOUT = HIN - 2, WOUT = WIN - 2, POUT = HOUT * WOUT;
    const int n0  = blockIdx.x * 256;
    const int tid = threadIdx.x;
    const int wid = tid >> 6, lane = tid & 63;
    const int wr = wid >> 2, wc = wid & 3;

    __shared__ __align__(16) __hip_bfloat16 lA[4 * 8192];  // 4 bufs of [256][32]
    __shared__ __align__(16) __hip_bfloat16 lB[4 * 8192];

    const int arow = tid >> 2;                       // 0..127
    const int seg  = (tid & 3) ^ ((tid >> 3) & 3);   // inverse slot-swizzle

    const size_t wbase0 = (size_t)arow * 2304 + seg * 8;
    const size_t wbase1 = (size_t)(arow + 128) * 2304 + seg * 8;

    int nr0 = n0 + arow;       if (nr0 > NTOT - 1) nr0 = NTOT - 1;
    int nr1 = n0 + arow + 128; if (nr1 > NTOT - 1) nr1 = NTOT - 1;
    int b0 = nr0 / POUT, p0 = nr0 % POUT, oy0 = p0 / WOUT, ox0 = p0 % WOUT;
    int b1 = nr1 / POUT, p1 = nr1 % POUT, oy1 = p1 / WOUT, ox1 = p1 % WOUT;
    const size_t xbase0 = (((size_t)b0 * HIN + oy0) * WIN + ox0) * 256 + seg * 8;
    const size_t xbase1 = (((size_t)b1 * HIN + oy1) * WIN + ox1) * 256 + seg * 8;

    auto stage = [&](int c0, int j, int sel) {
        char* a0 = (char*)lA + sel * 16384 + wid * 1024;
        char* b0p = (char*)lB + sel * 16384 + wid * 1024;
        const int woff = j * 256 + c0;
        gld_lds16(wt + wbase0 + woff, a0);
        gld_lds16(wt + wbase1 + woff, a0 + 8192);
        const int xoff = ((j / 3) * WIN + (j % 3)) * 256 + c0;
        gld_lds16(xt + xbase0 + xoff, b0p);
        gld_lds16(xt + xbase1 + xoff, b0p + 8192);
    };

    f32x4 acc[8][4];
#pragma unroll
    for (int i = 0; i < 8; ++i)
#pragma unroll
        for (int j = 0; j < 4; ++j)
            acc[i][j] = f32x4{0.f, 0.f, 0.f, 0.f};

    const int l15 = lane & 15, l16 = lane >> 4;
    const int slot = l16 ^ ((l15 >> 1) & 3);
    const int aoff = (wr * 128 + l15) * 32 + slot * 8;
    const int boff = (wc * 64  + l15) * 32 + slot * 8;

    bf16x8 pA0[4], pA4[4], pB[4], qA0[4], qA4[4], qB[4];

    stage(0, 0, 0); stage(0, 1, 1); stage(0, 2, 2);
    int js = 3, c0s = 0;  // stage cursor for step t+3
    WAITVM8; BAR();
    RD8(pA0, pB, 0);

#define ADV do { ++js; if (js == 9) { js = 0; c0s += 32; } } while (0)
    for (int tt = 0; tt < 17; ++tt) {
        STEP(pA0, pA4, pB, qA0, qB, 0, stage(c0s, js, 3), WAITVM8, true); ADV;
        STEP(qA0, qA4, qB, pA0, pB, 1, stage(c0s, js, 0), WAITVM8, true); ADV;
        STEP(pA0, pA4, pB, qA0, qB, 2, stage(c0s, js, 1), WAITVM8, true); ADV;
        STEP(qA0, qA4, qB, pA0, pB, 3, stage(c0s, js, 2), WAITVM8, true); ADV;
    }
    STEP(pA0, pA4, pB, qA0, qB, 0, stage(c0s, js, 3), WAITVM8, true);
    STEP(qA0, qA4, qB, pA0, pB, 1, (void)0,           WAITVM4, true);
    STEP(pA0, pA4, pB, qA0, qB, 2, (void)0,           WAITVM0, true);
    STEP(qA0, qA4, qB, pA0, pB, 3, (void)0,           (void)0, false);
#undef ADV

#pragma unroll
    for (int i = 0; i < 8; ++i) {
        const int co_b = wr * 128 + i * 16 + l16 * 4;
        float sc[4], sh[4];
#pragma unroll
        for (int r = 0; r < 4; ++r) {
            sc[r] = g[co_b + r] * rsqrtf(vv[co_b + r] + EPS);
            sh[r] = bb[co_b + r] - mm_[co_b + r] * sc[r];
        }
#pragma unroll
        for (int jj = 0; jj < 4; ++jj) {
            const int n = n0 + wc * 64 + jj * 16 + l15;
            if (n < NTOT) {
                u16x4 o;
#pragma unroll
                for (int r = 0; r < 4; ++r) {
                    const float v = fmaxf(fmaf(acc[i][jj][r], sc[r], sh[r]), 0.f);
                    __hip_bfloat16 hv = __float2bfloat16(v);
                    o[r] = *reinterpret_cast<unsigned short*>(&hv);
                }
                *reinterpret_cast<u16x4*>(&y[(size_t)n * 256 + co_b]) = o;
            }
        }
    }
}

// ---------------- conv3x3 kernel-branch: split-K partial ----------------
__global__ __launch_bounds__(256, 2) void conv3x3_partial(
    const __hip_bfloat16* __restrict__ xt,  // [B][7][7][256]
    const __hip_bfloat16* __restrict__ wt,  // [256][9][256]
    float* __restrict__ part)               // [4][3200][256]
{
    constexpr int HIN = 7, WIN = 7, POUT = 25;
    const int n0  = blockIdx.x * 128;
    const int kc0 = blockIdx.y * 64;
    const int kidx = blockIdx.y;
    const int tid = threadIdx.x;
    const int wid = tid >> 6, lane = tid & 63;
    const int wr = wid >> 1, wc = wid & 1;

    __shared__ __align__(16) __hip_bfloat16 sA[3 * 8192];
    __shared__ __align__(16) __hip_bfloat16 sB[3 * 4096];

    const int srow = wid * 16 + (lane >> 2);
    const int seg  = (lane & 3) ^ ((lane >> 3) & 3);

    const size_t wbase = (size_t)srow * 2304 + seg * 8;
    int nr0 = n0 + srow;
    int b0 = nr0 / POUT, p0 = nr0 % POUT, oy0 = p0 / 5, ox0 = p0 % 5;
    const size_t xbase0 = (((size_t)b0 * HIN + oy0) * WIN + ox0) * 256 + seg * 8;
    int nr1 = nr0 + 64;
    int b1 = nr1 / POUT, p1 = nr1 % POUT, oy1 = p1 / 5, ox1 = p1 % 5;
    const size_t xbase1 = (((size_t)b1 * HIN + oy1) * WIN + ox1) * 256 + seg * 8;

    auto stage = [&](int c0, int j, int sel) {
        char* a0 = (char*)sA + sel * 16384 + wid * 1024;
        char* b0p = (char*)sB + sel * 8192 + wid * 1024;
        const int woff = j * 256 + c0;
        gld_lds16(wt + wbase + woff,              a0);
        gld_lds16(wt + wbase + 64 * 2304 + woff,  a0 + 4096);
        gld_lds16(wt + wbase + 128 * 2304 + woff, a0 + 8192);
        gld_lds16(wt + wbase + 192 * 2304 + woff, a0 + 12288);
        const int xoff = ((j / 3) * WIN + (j % 3)) * 256 + c0;
        gld_lds16(xt + xbase0 + xoff, b0p);
        gld_lds16(xt + xbase1 + xoff, b0p + 4096);
    };

    f32x4 acc[8][4];
#pragma unroll
    for (int i = 0; i < 8; ++i)
#pragma unroll
        for (int j = 0; j < 4; ++j)
            acc[i][j] = f32x4{0.f, 0.f, 0.f, 0.f};

    const int l15 = lane & 15, l16 = lane >> 4;
    const int slot = l16 ^ ((l15 >> 1) & 3);
    const int aoffp = (wr * 128 + l15) * 32 + slot * 8;
    const int boffp = (wc * 64  + l15) * 32 + slot * 8;

    auto compute = [&](int sel) {
        const int ab = sel * 8192, bb_ = sel * 4096;
        bf16x8 b[4];
#pragma unroll
        for (int j = 0; j < 4; ++j)
            b[j] = *reinterpret_cast<const bf16x8*>(&sB[bb_ + boffp + j * 512]);
#pragma unroll
        for (int i = 0; i < 8; ++i) {
            bf16x8 a = *reinterpret_cast<const bf16x8*>(&sA[ab + aoffp + i * 512]);
#pragma unroll
            for (int j = 0; j < 4; ++j)
                acc[i][j] = __builtin_amdgcn_mfma_f32_16x16x32_bf16(
                    a, b[j], acc[i][j], 0, 0, 0);
        }
    };

    stage(kc0, 0, 0); stage(kc0, 1, 1);
    int js = 2, c0s = kc0;
    for (int t = 0; t < 16; ++t) {
        WAITVM6; BAR();
        stage(c0s, js, (t + 2) % 3);
        ++js; if (js == 9) { js = 0; c0s += 32; }
        compute(t % 3);
    }
    WAITVM6; BAR(); compute(16 % 3);
    WAITVM0; BAR(); compute(17 % 3);

#pragma unroll
    for (int i = 0; i < 8; ++i) {
        const int co_b = wr * 128 + i * 16 + l16 * 4;
#pragma unroll
        for (int jj = 0; jj < 4; ++jj) {
            const int n = n0 + wc * 64 + jj * 16 + l15;
            f32x4 o = acc[i][jj];
            *reinterpret_cast<f32x4*>(
                &part[((size_t)kidx * 3200 + n) * 256 + co_b]) = o;
        }
    }
}

// ---------------- reduce split-K partials + BN + ReLU -> y1 bf16
__global__ __launch_bounds__(256) void reduce_bn_relu(
    const float* __restrict__ part,  // [4][3200][256]
    const float* __restrict__ g, const float* __restrict__ bb,
    const float* __restrict__ mm_, const float* __restrict__ vv,
    __hip_bfloat16* __restrict__ y1) // [3200][256]
{
    const int n = blockIdx.x, co = threadIdx.x;
    float s = part[(size_t)n * 256 + co]
            + part[((size_t)3200 + n) * 256 + co]
            + part[((size_t)6400 + n) * 256 + co]
            + part[((size_t)9600 + n) * 256 + co];
    const float sc = g[co] * rsqrtf(vv[co] + EPS);
    const float sh = bb[co] - mm_[co] * sc;
    y1[(size_t)n * 256 + co] = __float2bfloat16(fmaxf(fmaf(s, sc, sh), 0.f));
}

// ---------------- depthwise xcorr 5x5, NHWC, bf16x2 vectorized ----------------
__global__ __launch_bounds__(128) void xcorr_dw_nhwc2(
    const __hip_bfloat16* __restrict__ s,  // [B][841][256]
    const __hip_bfloat16* __restrict__ k,  // [B][25][256]
    __hip_bfloat16* __restrict__ f)        // [B][625][256]
{
    const int py = blockIdx.x, b = blockIdx.y, c2 = threadIdx.x;  // ch pair
    const ushort2* sp = reinterpret_cast<const ushort2*>(s + (size_t)b * 841 * 256) + c2;
    const ushort2* kp = reinterpret_cast<const ushort2*>(k + (size_t)b * 25 * 256) + c2;

    float a0[25], a1[25];
#pragma unroll
    for (int i = 0; i < 25; ++i) { a0[i] = 0.f; a1[i] = 0.f; }

    for (int ky = 0; ky < 5; ++ky) {
        const ushort2* srp = sp + (size_t)(py + ky) * 29 * 128;
        float s0[29], s1[29];
#pragma unroll
        for (int rx = 0; rx < 29; ++rx) {
            ushort2 u = srp[(size_t)rx * 128];
            unsigned int w0 = (unsigned int)u.x << 16, w1 = (unsigned int)u.y << 16;
            s0[rx] = *reinterpret_cast<float*>(&w0);
            s1[rx] = *reinterpret_cast<float*>(&w1);
        }
#pragma unroll
        for (int kx = 0; kx < 5; ++kx) {
            ushort2 u = kp[(size_t)(ky * 5 + kx) * 128];
            unsigned int w0 = (unsigned int)u.x << 16, w1 = (unsigned int)u.y << 16;
            const float k0 = *reinterpret_cast<float*>(&w0);
            const float k1 = *reinterpret_cast<float*>(&w1);
#pragma unroll
            for (int px = 0; px < 25; ++px) {
                a0[px] = fmaf(s0[px + kx], k0, a0[px]);
                a1[px] = fmaf(s1[px + kx], k1, a1[px]);
            }
        }
    }

    ushort2* fp = reinterpret_cast<ushort2*>(f + ((size_t)b * 625 + (size_t)py * 25) * 256) + c2;
#pragma unroll
    for (int px = 0; px < 25; ++px) {
        __hip_bfloat16 h0 = __float2bfloat16(a0[px]);
        __hip_bfloat16 h1 = __float2bfloat16(a1[px]);
        ushort2 o;
        o.x = *reinterpret_cast<unsigned short*>(&h0);
        o.y = *reinterpret_cast<unsigned short*>(&h1);
        fp[(size_t)px * 128] = o;
    }
}

// ---------------- head: 1x1 conv (MFMA) + BN + ReLU + 1x1 conv (256->10) -----
// GEMM M=256, N=80000 (313 tiles of 256), K=256 (8 K32 steps, R9 pipeline).
// Layer-2 fused in epilogue: block holds ALL 256 co for its pixels, so
// out[o][n] = b2[o] + sum_co w2[o][co]*relu(bn(h)) is block-local:
// per-lane 32-co partial dot (w2 in LDS) -> shfl_xor over l16 -> LDS bounce
// across the two M-waves -> direct f32 store. No h buffer, no head2 kernel.
__global__ __launch_bounds__(512) void head_fused8(
    const __hip_bfloat16* __restrict__ f,   // [N][256]
    const __hip_bfloat16* __restrict__ w1,  // [256][256] bf16
    const float* __restrict__ g, const float* __restrict__ bb,
    const float* __restrict__ mm_, const float* __restrict__ vv,
    const float* __restrict__ w2,           // [10][256]
    const float* __restrict__ b2v,          // [10]
    float* __restrict__ out)                // [B][10][25][25]
{
    constexpr int NTOT = 80000;
    const int n0  = blockIdx.x * 256;
    const int tid = threadIdx.x;
    const int wid = tid >> 6, lane = tid & 63;
    const int wr = wid >> 2, wc = wid & 3;

    __shared__ __align__(16) __hip_bfloat16 lA[4 * 8192];
    __shared__ __align__(16) __hip_bfloat16 lB[4 * 8192];

    const int arow = tid >> 2;
    const int seg  = (tid & 3) ^ ((tid >> 3) & 3);

    const size_t wbase0 = (size_t)arow * 256 + seg * 8;
    const size_t wbase1 = (size_t)(arow + 128) * 256 + seg * 8;
    int nr0 = n0 + arow;       if (nr0 > NTOT - 1) nr0 = NTOT - 1;
    int nr1 = n0 + arow + 128; if (nr1 > NTOT - 1) nr1 = NTOT - 1;
    const size_t xbase0 = (size_t)nr0 * 256 + seg * 8;
    const size_t xbase1 = (size_t)nr1 * 256 + seg * 8;

    auto stage = [&](int c0, int sel) {
        char* a0 = (char*)lA + sel * 16384 + wid * 1024;
        char* b0p = (char*)lB + sel * 16384 + wid * 1024;
        gld_lds16(w1 + wbase0 + c0, a0);
        gld_lds16(w1 + wbase1 + c0, a0 + 8192);
        gld_lds16(f + xbase0 + c0, b0p);
        gld_lds16(f + xbase1 + c0, b0p + 8192);
    };

    f32x4 acc[8][4];
#pragma unroll
    for (int i = 0; i < 8; ++i)
#pragma unroll
        for (int j = 0; j < 4; ++j)
            acc[i][j] = f32x4{0.f, 0.f, 0.f, 0.f};

    const int l15 = lane & 15, l16 = lane >> 4;
    const int slot = l16 ^ ((l15 >> 1) & 3);
    const int aoff = (wr * 128 + l15) * 32 + slot * 8;
    const int boff = (wc * 64  + l15) * 32 + slot * 8;

    bf16x8 pA0[4], pA4[4], pB[4], qA0[4], qA4[4], qB[4];

    stage(0, 0); stage(32, 1); stage(64, 2);
    WAITVM8; BAR();
    RD8(pA0, pB, 0);

    STEP(pA0, pA4, pB, qA0, qB, 0, stage(96, 3),  WAITVM8, true);   // t=0
    STEP(qA0, qA4, qB, pA0, pB, 1, stage(128, 0), WAITVM8, true);   // t=1
    STEP(pA0, pA4, pB, qA0, qB, 2, stage(160, 1), WAITVM8, true);   // t=2
    STEP(qA0, qA4, qB, pA0, pB, 3, stage(192, 2), WAITVM8, true);   // t=3
    STEP(pA0, pA4, pB, qA0, qB, 0, stage(224, 3), WAITVM8, true);   // t=4
    STEP(qA0, qA4, qB, pA0, pB, 1, (void)0,       WAITVM4, true);   // t=5
    STEP(pA0, pA4, pB, qA0, qB, 2, (void)0,       WAITVM0, true);   // t=6
    STEP(qA0, qA4, qB, pA0, pB, 3, (void)0,       (void)0, false);  // t=7

    // ---- fused layer-2 epilogue ----
    __syncthreads();                 // all waves done reading lA/lB
    float* lw   = (float*)lA;        // [10][256] w2, then [10] b2
    float* lred = (float*)lB;        // [4 wc][4 jj][16 l15][10 o] wr=0 partials
    for (int t = tid; t < 2560; t += 512) lw[t] = w2[t];
    if (tid < 10) lw[2560 + tid] = b2v[tid];
    __syncthreads();

    float p[4][10];
#pragma unroll
    for (int jj = 0; jj < 4; ++jj)
#pragma unroll
        for (int o = 0; o < 10; ++o) p[jj][o] = 0.f;

#pragma unroll
    for (int i = 0; i < 8; ++i) {
        const int co_b = wr * 128 + i * 16 + l16 * 4;
        float sc[4], sh[4];
#pragma unroll
        for (int r = 0; r < 4; ++r) {
            sc[r] = g[co_b + r] * rsqrtf(vv[co_b + r] + EPS);
            sh[r] = bb[co_b + r] - mm_[co_b + r] * sc[r];
        }
        float w4[10][4];
#pragma unroll
        for (int o = 0; o < 10; ++o) {
            f32x4 wv = *reinterpret_cast<const f32x4*>(&lw[o * 256 + co_b]);
#pragma unroll
            for (int r = 0; r < 4; ++r) w4[o][r] = wv[r];
        }
#pragma unroll
        for (int jj = 0; jj < 4; ++jj) {
            float hv[4];
#pragma unroll
            for (int r = 0; r < 4; ++r)
                hv[r] = fmaxf(fmaf(acc[i][jj][r], sc[r], sh[r]), 0.f);
#pragma unroll
            for (int o = 0; o < 10; ++o)
#pragma unroll
                for (int r = 0; r < 4; ++r)
                    p[jj][o] = fmaf(hv[r], w4[o][r], p[jj][o]);
        }
    }

    // reduce across l16 groups (co spread over 4 lanes at stride 16)
#pragma unroll
    for (int jj = 0; jj < 4; ++jj)
#pragma unroll
        for (int o = 0; o < 10; ++o) {
            float v = p[jj][o];
            v += __shfl_xor(v, 16, 64);
            v += __shfl_xor(v, 32, 64);
            p[jj][o] = v;
        }

    // cross-wave (wr) reduce via LDS
    if (wr == 0 && l16 == 0) {
#pragma unroll
        for (int jj = 0; jj < 4; ++jj)
#pragma unroll
            for (int o = 0; o < 10; ++o)
                lred[((wc * 4 + jj) * 16 + l15) * 10 + o] = p[jj][o];
    }
    __syncthreads();
    if (wr == 1) {
#pragma unroll
        for (int jj = 0; jj < 4; ++jj) {
            const int n = n0 + wc * 64 + jj * 16 + l15;
            if (n < NTOT) {
                const int bi = n / 625, pp = n % 625;
#pragma unroll
                for (int t = 0; t < 3; ++t) {
                    const int o = l16 + 4 * t;
                    if (o < 10) {
                        float v = p[jj][o]
                                + lred[((wc * 4 + jj) * 16 + l15) * 10 + o]
                                + lw[2560 + o];
                        out[((size_t)bi * 10 + o) * 625 + pp] = v;
                    }
                }
            }
        }
    }
}

extern "C" void kernel_launch(void* const* d_in, const int* in_sizes, int n_in,
                              void* d_out, int out_size, void* d_ws, size_t ws_size,
                              hipStream_t stream) {
    const float* kernel = (const float*)d_in[0];   // [128,256,7,7]
    const float* search = (const float*)d_in[1];   // [128,256,31,31]
    const float* w_ck   = (const float*)d_in[2];
    const float* g1 = (const float*)d_in[3];
    const float* b1 = (const float*)d_in[4];
    const float* m1 = (const float*)d_in[5];
    const float* v1 = (const float*)d_in[6];
    const float* w_cs   = (const float*)d_in[7];
    const float* g2 = (const float*)d_in[8];
    const float* b2 = (const float*)d_in[9];
    const float* m2 = (const float*)d_in[10];
    const float* v2 = (const float*)d_in[11];
    const float* w_h1   = (const float*)d_in[12];
    const float* g3 = (const float*)d_in[13];
    const float* b3 = (const float*)d_in[14];
    const float* m3 = (const float*)d_in[15];
    const float* v3 = (const float*)d_in[16];
    const float* w_h2   = (const float*)d_in[17];
    const float* b_h2   = (const float*)d_in[18];

    float* out = (float*)d_out;

    __hip_bfloat16* ws = (__hip_bfloat16*)d_ws;
    __hip_bfloat16* y1    = ws;
    __hip_bfloat16* y2    = ws + (size_t)819200;
    float*          part  = (float*)(ws + (size_t)819200);
    __hip_bfloat16* wt_ck = ws + (size_t)28377088;
    __hip_bfloat16* wt_cs = ws + (size_t)28966912;
    __hip_bfloat16* wh1   = ws + (size_t)29556736;
    __hip_bfloat16* xt_k  = ws + (size_t)29622272;
    __hip_bfloat16* xt_s  = ws + (size_t)31227904;
    __hip_bfloat16* feat  = ws + (size_t)29622272;

    (void)in_sizes; (void)n_in; (void)out_size; (void)ws_size;

    // pre-passes
    wt_transpose_bf16<<<256, 256, 0, stream>>>(w_ck, wt_ck);
    wt_transpose_bf16<<<256, 256, 0, stream>>>(w_cs, wt_cs);
    f32_to_bf16<<<256, 256, 0, stream>>>(w_h1, wh1, 65536);
    nchw_to_nhwc_v2<<<dim3(2, 128), 256, 0, stream>>>(kernel, xt_k, 49);
    nchw_to_nhwc_v2<<<dim3(31, 128), 256, 0, stream>>>(search, xt_s, 961);

    // kernel branch: split-K x4 partials (into y2 region) + reduce -> y1
    conv3x3_partial<<<dim3(25, 4), 256, 0, stream>>>(xt_k, wt_ck, part);
    reduce_bn_relu<<<3200, 256, 0, stream>>>(part, g1, b1, m1, v1, y1);

    // search branch: pipelined implicit GEMM -> y2 (N=107648, 421 tiles)
    conv3x3_mfma8<31, 31, 107648><<<421, 512, 0, stream>>>(
        xt_s, wt_cs, g2, b2, m2, v2, y2);

    // depthwise xcorr -> feat NHWC
    xcorr_dw_nhwc2<<<dim3(25, 128), 128, 0, stream>>>(y2, y1, feat);

    // fused head (layer1 MFMA + BN + ReLU + layer2 dot) -> out directly
    head_fused8<<<313, 512, 0, stream>>>(feat, wh1, g3, b3, m3, v3, w_h2, b_h2, out);
}

// Round 12
// 315.193 us; speedup vs baseline: 1.1432x; 1.1219x over previous
//
#include <hip/hip_runtime.h>
#include <hip/hip_bf16.h>

#define EPS 1e-5f

typedef __attribute__((ext_vector_type(8))) short bf16x8;
typedef __attribute__((ext_vector_type(4))) float f32x4;
typedef __attribute__((ext_vector_type(4))) unsigned short u16x4;
typedef __attribute__((ext_vector_type(8))) unsigned short u16x8;

#define WAITVM8 asm volatile("s_waitcnt vmcnt(8)" ::: "memory")
#define WAITVM4 asm volatile("s_waitcnt vmcnt(4)" ::: "memory")
#define WAITVM0 asm volatile("s_waitcnt vmcnt(0)" ::: "memory")
#define BAR()   __builtin_amdgcn_s_barrier()

// ---- async global->LDS, 16B per lane, linear dest (wave-uniform base + lane*16)
__device__ __forceinline__ void gld_lds16(const void* g, void* l) {
    __builtin_amdgcn_global_load_lds(
        (const __attribute__((address_space(1))) unsigned int*)g,
        (__attribute__((address_space(3))) unsigned int*)l, 16, 0, 0);
}

// ---- GEMM step macros (R9 schedule: 1 barrier + 1 counted vm-wait per K32).
#define RD8(RA, RB, SEL) do {                                                  \
    const int _b = (SEL) * 8192;                                               \
    _Pragma("unroll") for (int _i = 0; _i < 4; ++_i)                           \
        RA[_i] = *reinterpret_cast<const bf16x8*>(&lA[_b + aoff + _i * 512]);  \
    _Pragma("unroll") for (int _j = 0; _j < 4; ++_j)                           \
        RB[_j] = *reinterpret_cast<const bf16x8*>(&lB[_b + boff + _j * 512]);  \
} while (0)

#define RD4(RA4, SEL) do {                                                     \
    const int _b = (SEL) * 8192;                                               \
    _Pragma("unroll") for (int _i = 0; _i < 4; ++_i)                           \
        RA4[_i] = *reinterpret_cast<const bf16x8*>(                            \
            &lA[_b + aoff + (_i + 4) * 512]);                                  \
} while (0)

#define MFQ(RA, RB, I0) do {                                                   \
    _Pragma("unroll") for (int _i = 0; _i < 4; ++_i)                           \
    _Pragma("unroll") for (int _j = 0; _j < 4; ++_j)                           \
        acc[(I0) + _i][_j] = __builtin_amdgcn_mfma_f32_16x16x32_bf16(          \
            RA[_i], RB[_j], acc[(I0) + _i][_j], 0, 0, 0);                      \
} while (0)

#define STEP(CA0, CA4, CB, NA0, NB, SELT, STAGE_STMT, WAIT_STMT, DORD) do {    \
    RD4(CA4, (SELT));                                                          \
    STAGE_STMT;                                                                \
    __builtin_amdgcn_s_setprio(1); MFQ(CA0, CB, 0);                            \
    __builtin_amdgcn_s_setprio(0);                                             \
    WAIT_STMT;                                                                 \
    BAR();                                                                     \
    if (DORD) RD8(NA0, NB, ((SELT) + 1) & 3);                                  \
    __builtin_amdgcn_s_setprio(1); MFQ(CA4, CB, 4);                            \
    __builtin_amdgcn_s_setprio(0);                                             \
} while (0)

// =============== conv3x3 implicit-GEMM device body (R9 schedule) =============
// M=256 (full), N-tile=256 px, K=2304 (72 K32 steps). 8 waves (2M x 4N),
// per-wave 128x64. 4 LDS bufs, depth-3 staging, counted vmcnt(8),
// 1 barrier/step, frag reads split 4+8, slot-swizzled LDS, fused BN+ReLU.
template<int HIN, int WIN, int NTOT>
__device__ __forceinline__ void conv_dev(
    int bid, int tid,
    __hip_bfloat16* lA, __hip_bfloat16* lB,
    const __hip_bfloat16* __restrict__ xt,  // [B][HIN][WIN][256]
    const __hip_bfloat16* __restrict__ wt,  // [256][9][256]
    const float* __restrict__ g, const float* __restrict__ bb,
    const float* __restrict__ mm_, const float* __restrict__ vv,
    __hip_bfloat16* __restrict__ y)         // NHWC: [NTOT][256]
{
    constexpr int HOUT = HIN - 2, WOUT = WIN - 2, POUT = HOUT * WOUT;
    const int n0  = bid * 256;
    const int wid = tid >> 6, lane = tid & 63;
    const int wr = wid >> 2, wc = wid & 3;

    const int arow = tid >> 2;                       // 0..127
    const int seg  = (tid & 3) ^ ((tid >> 3) & 3);   // inverse slot-swizzle

    const size_t wbase0 = (size_t)arow * 2304 + seg * 8;
    const size_t wbase1 = (size_t)(arow + 128) * 2304 + seg * 8;

    int nr0 = n0 + arow;       if (nr0 > NTOT - 1) nr0 = NTOT - 1;
    int nr1 = n0 + arow + 128; if (nr1 > NTOT - 1) nr1 = NTOT - 1;
    int b0 = nr0 / POUT, p0 = nr0 % POUT, oy0 = p0 / WOUT, ox0 = p0 % WOUT;
    int b1 = nr1 / POUT, p1 = nr1 % POUT, oy1 = p1 / WOUT, ox1 = p1 % WOUT;
    const size_t xbase0 = (((size_t)b0 * HIN + oy0) * WIN + ox0) * 256 + seg * 8;
    const size_t xbase1 = (((size_t)b1 * HIN + oy1) * WIN + ox1) * 256 + seg * 8;

    auto stage = [&](int c0, int j, int sel) {
        char* a0 = (char*)lA + sel * 16384 + wid * 1024;
        char* b0p = (char*)lB + sel * 16384 + wid * 1024;
        const int woff = j * 256 + c0;
        gld_lds16(wt + wbase0 + woff, a0);
        gld_lds16(wt + wbase1 + woff, a0 + 8192);
        const int xoff = ((j / 3) * WIN + (j % 3)) * 256 + c0;
        gld_lds16(xt + xbase0 + xoff, b0p);
        gld_lds16(xt + xbase1 + xoff, b0p + 8192);
    };

    f32x4 acc[8][4];
#pragma unroll
    for (int i = 0; i < 8; ++i)
#pragma unroll
        for (int j = 0; j < 4; ++j)
            acc[i][j] = f32x4{0.f, 0.f, 0.f, 0.f};

    const int l15 = lane & 15, l16 = lane >> 4;
    const int slot = l16 ^ ((l15 >> 1) & 3);
    const int aoff = (wr * 128 + l15) * 32 + slot * 8;
    const int boff = (wc * 64  + l15) * 32 + slot * 8;

    bf16x8 pA0[4], pA4[4], pB[4], qA0[4], qA4[4], qB[4];

    stage(0, 0, 0); stage(0, 1, 1); stage(0, 2, 2);
    int js = 3, c0s = 0;  // stage cursor for step t+3
    WAITVM8; BAR();
    RD8(pA0, pB, 0);

#define ADVC do { ++js; if (js == 9) { js = 0; c0s += 32; } } while (0)
    for (int tt = 0; tt < 17; ++tt) {
        STEP(pA0, pA4, pB, qA0, qB, 0, stage(c0s, js, 3), WAITVM8, true); ADVC;
        STEP(qA0, qA4, qB, pA0, pB, 1, stage(c0s, js, 0), WAITVM8, true); ADVC;
        STEP(pA0, pA4, pB, qA0, qB, 2, stage(c0s, js, 1), WAITVM8, true); ADVC;
        STEP(qA0, qA4, qB, pA0, pB, 3, stage(c0s, js, 2), WAITVM8, true); ADVC;
    }
    STEP(pA0, pA4, pB, qA0, qB, 0, stage(c0s, js, 3), WAITVM8, true);
    STEP(qA0, qA4, qB, pA0, pB, 1, (void)0,           WAITVM4, true);
    STEP(pA0, pA4, pB, qA0, qB, 2, (void)0,           WAITVM0, true);
    STEP(qA0, qA4, qB, pA0, pB, 3, (void)0,           (void)0, false);
#undef ADVC

#pragma unroll
    for (int i = 0; i < 8; ++i) {
        const int co_b = wr * 128 + i * 16 + l16 * 4;
        float sc[4], sh[4];
#pragma unroll
        for (int r = 0; r < 4; ++r) {
            sc[r] = g[co_b + r] * rsqrtf(vv[co_b + r] + EPS);
            sh[r] = bb[co_b + r] - mm_[co_b + r] * sc[r];
        }
#pragma unroll
        for (int jj = 0; jj < 4; ++jj) {
            const int n = n0 + wc * 64 + jj * 16 + l15;
            if (n < NTOT) {
                u16x4 o;
#pragma unroll
                for (int r = 0; r < 4; ++r) {
                    const float v = fmaxf(fmaf(acc[i][jj][r], sc[r], sh[r]), 0.f);
                    __hip_bfloat16 hv = __float2bfloat16(v);
                    o[r] = *reinterpret_cast<unsigned short*>(&hv);
                }
                *reinterpret_cast<u16x4*>(&y[(size_t)n * 256 + co_b]) = o;
            }
        }
    }
}

// ---------------- conv_both: search blocks 0..420, kernel blocks 421..433 ----
__global__ __launch_bounds__(512, 2) void conv_both(
    const __hip_bfloat16* __restrict__ xt_s, const __hip_bfloat16* __restrict__ wt_cs,
    const float* __restrict__ g2, const float* __restrict__ b2,
    const float* __restrict__ m2, const float* __restrict__ v2,
    __hip_bfloat16* __restrict__ y2,
    const __hip_bfloat16* __restrict__ xt_k, const __hip_bfloat16* __restrict__ wt_ck,
    const float* __restrict__ g1, const float* __restrict__ b1,
    const float* __restrict__ m1, const float* __restrict__ v1,
    __hip_bfloat16* __restrict__ y1)
{
    __shared__ __align__(16) __hip_bfloat16 lA[4 * 8192];
    __shared__ __align__(16) __hip_bfloat16 lB[4 * 8192];
    if (blockIdx.x < 421)
        conv_dev<31, 31, 107648>(blockIdx.x, threadIdx.x, lA, lB,
                                 xt_s, wt_cs, g2, b2, m2, v2, y2);
    else
        conv_dev<7, 7, 3200>(blockIdx.x - 421, threadIdx.x, lA, lB,
                             xt_k, wt_ck, g1, b1, m1, v1, y1);
}

// =============== merged pre-pass kernel ======================================
// blocks 0..255:    wt_transpose w_ck -> wt_ck
// blocks 256..511:  wt_transpose w_cs -> wt_cs
// blocks 512..767:  f32->bf16 w_h1 -> wh1
// blocks 768..1023: nchw->nhwc kernel (P=49), idx=(bid-768): bx=idx&1, b=idx>>1
// blocks 1024..4991: nchw->nhwc search (P=961), idx: bx=idx%31, b=idx/31
__device__ __forceinline__ void nhwc_body(
    const float* __restrict__ x, __hip_bfloat16* __restrict__ xt, int P,
    int bx, int b, float* t /* [256*33] */)
{
    const int p0 = bx * 32;
    const float* xb = x + (size_t)b * 256 * P;
    const int pl = threadIdx.x & 31, cg = threadIdx.x >> 5;
#pragma unroll
    for (int it = 0; it < 32; ++it) {
        int c = cg + it * 8, p = p0 + pl;
        t[c * 33 + pl] = (p < P) ? xb[(size_t)c * P + p] : 0.f;
    }
    __syncthreads();
    const int p = threadIdx.x >> 3, l8 = threadIdx.x & 7;
    if (p0 + p < P) {
        __hip_bfloat16* xo = xt + ((size_t)b * P + p0 + p) * 256;
#pragma unroll
        for (int j = 0; j < 4; ++j) {
            const int c0 = j * 64 + l8 * 8;
            u16x8 o;
#pragma unroll
            for (int r = 0; r < 8; ++r) {
                __hip_bfloat16 hv = __float2bfloat16(t[(c0 + r) * 33 + p]);
                o[r] = *reinterpret_cast<unsigned short*>(&hv);
            }
            *reinterpret_cast<u16x8*>(&xo[c0]) = o;
        }
    }
}

__global__ __launch_bounds__(256) void prepass(
    const float* __restrict__ w_ck, __hip_bfloat16* __restrict__ wt_ck,
    const float* __restrict__ w_cs, __hip_bfloat16* __restrict__ wt_cs,
    const float* __restrict__ w_h1, __hip_bfloat16* __restrict__ wh1,
    const float* __restrict__ kernel, __hip_bfloat16* __restrict__ xt_k,
    const float* __restrict__ search, __hip_bfloat16* __restrict__ xt_s)
{
    __shared__ float t[256 * 33];
    const int bid = blockIdx.x;
    if (bid < 512) {
        const float* w = (bid < 256) ? w_ck : w_cs;
        __hip_bfloat16* wt = (bid < 256) ? wt_ck : wt_cs;
        const int co = bid & 255, ci = threadIdx.x;
        const float* wp = w + (size_t)co * 2304 + (size_t)ci * 9;
        __hip_bfloat16* wo = wt + (size_t)co * 2304 + ci;
#pragma unroll
        for (int j = 0; j < 9; ++j)
            wo[(size_t)j * 256] = __float2bfloat16(wp[j]);
    } else if (bid < 768) {
        const int i = (bid - 512) * 256 + threadIdx.x;
        wh1[i] = __float2bfloat16(w_h1[i]);
    } else if (bid < 1024) {
        const int idx = bid - 768;
        nhwc_body(kernel, xt_k, 49, idx & 1, idx >> 1, t);
    } else {
        const int idx = bid - 1024;
        nhwc_body(search, xt_s, 961, idx % 31, idx / 31, t);
    }
}

// ---------------- depthwise xcorr 5x5, NHWC, bf16x2 vectorized ----------------
__global__ __launch_bounds__(128) void xcorr_dw_nhwc2(
    const __hip_bfloat16* __restrict__ s,  // [B][841][256]
    const __hip_bfloat16* __restrict__ k,  // [B][25][256]
    __hip_bfloat16* __restrict__ f)        // [B][625][256]
{
    const int py = blockIdx.x, b = blockIdx.y, c2 = threadIdx.x;  // ch pair
    const ushort2* sp = reinterpret_cast<const ushort2*>(s + (size_t)b * 841 * 256) + c2;
    const ushort2* kp = reinterpret_cast<const ushort2*>(k + (size_t)b * 25 * 256) + c2;

    float a0[25], a1[25];
#pragma unroll
    for (int i = 0; i < 25; ++i) { a0[i] = 0.f; a1[i] = 0.f; }

    for (int ky = 0; ky < 5; ++ky) {
        const ushort2* srp = sp + (size_t)(py + ky) * 29 * 128;
        float s0[29], s1[29];
#pragma unroll
        for (int rx = 0; rx < 29; ++rx) {
            ushort2 u = srp[(size_t)rx * 128];
            unsigned int w0 = (unsigned int)u.x << 16, w1 = (unsigned int)u.y << 16;
            s0[rx] = *reinterpret_cast<float*>(&w0);
            s1[rx] = *reinterpret_cast<float*>(&w1);
        }
#pragma unroll
        for (int kx = 0; kx < 5; ++kx) {
            ushort2 u = kp[(size_t)(ky * 5 + kx) * 128];
            unsigned int w0 = (unsigned int)u.x << 16, w1 = (unsigned int)u.y << 16;
            const float k0 = *reinterpret_cast<float*>(&w0);
            const float k1 = *reinterpret_cast<float*>(&w1);
#pragma unroll
            for (int px = 0; px < 25; ++px) {
                a0[px] = fmaf(s0[px + kx], k0, a0[px]);
                a1[px] = fmaf(s1[px + kx], k1, a1[px]);
            }
        }
    }

    ushort2* fp = reinterpret_cast<ushort2*>(f + ((size_t)b * 625 + (size_t)py * 25) * 256) + c2;
#pragma unroll
    for (int px = 0; px < 25; ++px) {
        __hip_bfloat16 h0 = __float2bfloat16(a0[px]);
        __hip_bfloat16 h1 = __float2bfloat16(a1[px]);
        ushort2 o;
        o.x = *reinterpret_cast<unsigned short*>(&h0);
        o.y = *reinterpret_cast<unsigned short*>(&h1);
        fp[(size_t)px * 128] = o;
    }
}

// ---------------- head: 1x1 conv (MFMA) + BN + ReLU + 1x1 conv (256->10) -----
__global__ __launch_bounds__(512) void head_fused8(
    const __hip_bfloat16* __restrict__ f,   // [N][256]
    const __hip_bfloat16* __restrict__ w1,  // [256][256] bf16
    const float* __restrict__ g, const float* __restrict__ bb,
    const float* __restrict__ mm_, const float* __restrict__ vv,
    const float* __restrict__ w2,           // [10][256]
    const float* __restrict__ b2v,          // [10]
    float* __restrict__ out)                // [B][10][25][25]
{
    constexpr int NTOT = 80000;
    const int n0  = blockIdx.x * 256;
    const int tid = threadIdx.x;
    const int wid = tid >> 6, lane = tid & 63;
    const int wr = wid >> 2, wc = wid & 3;

    __shared__ __align__(16) __hip_bfloat16 lA[4 * 8192];
    __shared__ __align__(16) __hip_bfloat16 lB[4 * 8192];

    const int arow = tid >> 2;
    const int seg  = (tid & 3) ^ ((tid >> 3) & 3);

    const size_t wbase0 = (size_t)arow * 256 + seg * 8;
    const size_t wbase1 = (size_t)(arow + 128) * 256 + seg * 8;
    int nr0 = n0 + arow;       if (nr0 > NTOT - 1) nr0 = NTOT - 1;
    int nr1 = n0 + arow + 128; if (nr1 > NTOT - 1) nr1 = NTOT - 1;
    const size_t xbase0 = (size_t)nr0 * 256 + seg * 8;
    const size_t xbase1 = (size_t)nr1 * 256 + seg * 8;

    auto stage = [&](int c0, int sel) {
        char* a0 = (char*)lA + sel * 16384 + wid * 1024;
        char* b0p = (char*)lB + sel * 16384 + wid * 1024;
        gld_lds16(w1 + wbase0 + c0, a0);
        gld_lds16(w1 + wbase1 + c0, a0 + 8192);
        gld_lds16(f + xbase0 + c0, b0p);
        gld_lds16(f + xbase1 + c0, b0p + 8192);
    };

    f32x4 acc[8][4];
#pragma unroll
    for (int i = 0; i < 8; ++i)
#pragma unroll
        for (int j = 0; j < 4; ++j)
            acc[i][j] = f32x4{0.f, 0.f, 0.f, 0.f};

    const int l15 = lane & 15, l16 = lane >> 4;
    const int slot = l16 ^ ((l15 >> 1) & 3);
    const int aoff = (wr * 128 + l15) * 32 + slot * 8;
    const int boff = (wc * 64  + l15) * 32 + slot * 8;

    bf16x8 pA0[4], pA4[4], pB[4], qA0[4], qA4[4], qB[4];

    stage(0, 0); stage(32, 1); stage(64, 2);
    WAITVM8; BAR();
    RD8(pA0, pB, 0);

    STEP(pA0, pA4, pB, qA0, qB, 0, stage(96, 3),  WAITVM8, true);   // t=0
    STEP(qA0, qA4, qB, pA0, pB, 1, stage(128, 0), WAITVM8, true);   // t=1
    STEP(pA0, pA4, pB, qA0, qB, 2, stage(160, 1), WAITVM8, true);   // t=2
    STEP(qA0, qA4, qB, pA0, pB, 3, stage(192, 2), WAITVM8, true);   // t=3
    STEP(pA0, pA4, pB, qA0, qB, 0, stage(224, 3), WAITVM8, true);   // t=4
    STEP(qA0, qA4, qB, pA0, pB, 1, (void)0,       WAITVM4, true);   // t=5
    STEP(pA0, pA4, pB, qA0, qB, 2, (void)0,       WAITVM0, true);   // t=6
    STEP(qA0, qA4, qB, pA0, pB, 3, (void)0,       (void)0, false);  // t=7

    // ---- fused layer-2 epilogue ----
    __syncthreads();                 // all waves done reading lA/lB
    float* lw   = (float*)lA;        // [10][256] w2, then [10] b2
    float* lred = (float*)lB;        // [4 wc][4 jj][16 l15][10 o] wr=0 partials
    for (int t = tid; t < 2560; t += 512) lw[t] = w2[t];
    if (tid < 10) lw[2560 + tid] = b2v[tid];
    __syncthreads();

    float p[4][10];
#pragma unroll
    for (int jj = 0; jj < 4; ++jj)
#pragma unroll
        for (int o = 0; o < 10; ++o) p[jj][o] = 0.f;

#pragma unroll
    for (int i = 0; i < 8; ++i) {
        const int co_b = wr * 128 + i * 16 + l16 * 4;
        float sc[4], sh[4];
#pragma unroll
        for (int r = 0; r < 4; ++r) {
            sc[r] = g[co_b + r] * rsqrtf(vv[co_b + r] + EPS);
            sh[r] = bb[co_b + r] - mm_[co_b + r] * sc[r];
        }
        float w4[10][4];
#pragma unroll
        for (int o = 0; o < 10; ++o) {
            f32x4 wv = *reinterpret_cast<const f32x4*>(&lw[o * 256 + co_b]);
#pragma unroll
            for (int r = 0; r < 4; ++r) w4[o][r] = wv[r];
        }
#pragma unroll
        for (int jj = 0; jj < 4; ++jj) {
            float hv[4];
#pragma unroll
            for (int r = 0; r < 4; ++r)
                hv[r] = fmaxf(fmaf(acc[i][jj][r], sc[r], sh[r]), 0.f);
#pragma unroll
            for (int o = 0; o < 10; ++o)
#pragma unroll
                for (int r = 0; r < 4; ++r)
                    p[jj][o] = fmaf(hv[r], w4[o][r], p[jj][o]);
        }
    }

    // reduce across l16 groups (co spread over 4 lanes at stride 16)
#pragma unroll
    for (int jj = 0; jj < 4; ++jj)
#pragma unroll
        for (int o = 0; o < 10; ++o) {
            float v = p[jj][o];
            v += __shfl_xor(v, 16, 64);
            v += __shfl_xor(v, 32, 64);
            p[jj][o] = v;
        }

    // cross-wave (wr) reduce via LDS
    if (wr == 0 && l16 == 0) {
#pragma unroll
        for (int jj = 0; jj < 4; ++jj)
#pragma unroll
            for (int o = 0; o < 10; ++o)
                lred[((wc * 4 + jj) * 16 + l15) * 10 + o] = p[jj][o];
    }
    __syncthreads();
    if (wr == 1) {
#pragma unroll
        for (int jj = 0; jj < 4; ++jj) {
            const int n = n0 + wc * 64 + jj * 16 + l15;
            if (n < NTOT) {
                const int bi = n / 625, pp = n % 625;
#pragma unroll
                for (int t = 0; t < 3; ++t) {
                    const int o = l16 + 4 * t;
                    if (o < 10) {
                        float v = p[jj][o]
                                + lred[((wc * 4 + jj) * 16 + l15) * 10 + o]
                                + lw[2560 + o];
                        out[((size_t)bi * 10 + o) * 625 + pp] = v;
                    }
                }
            }
        }
    }
}

extern "C" void kernel_launch(void* const* d_in, const int* in_sizes, int n_in,
                              void* d_out, int out_size, void* d_ws, size_t ws_size,
                              hipStream_t stream) {
    const float* kernel = (const float*)d_in[0];   // [128,256,7,7]
    const float* search = (const float*)d_in[1];   // [128,256,31,31]
    const float* w_ck   = (const float*)d_in[2];
    const float* g1 = (const float*)d_in[3];
    const float* b1 = (const float*)d_in[4];
    const float* m1 = (const float*)d_in[5];
    const float* v1 = (const float*)d_in[6];
    const float* w_cs   = (const float*)d_in[7];
    const float* g2 = (const float*)d_in[8];
    const float* b2 = (const float*)d_in[9];
    const float* m2 = (const float*)d_in[10];
    const float* v2 = (const float*)d_in[11];
    const float* w_h1   = (const float*)d_in[12];
    const float* g3 = (const float*)d_in[13];
    const float* b3 = (const float*)d_in[14];
    const float* m3 = (const float*)d_in[15];
    const float* v3 = (const float*)d_in[16];
    const float* w_h2   = (const float*)d_in[17];
    const float* b_h2   = (const float*)d_in[18];

    float* out = (float*)d_out;

    __hip_bfloat16* ws = (__hip_bfloat16*)d_ws;
    __hip_bfloat16* y1    = ws;
    __hip_bfloat16* y2    = ws + (size_t)819200;
    __hip_bfloat16* wt_ck = ws + (size_t)28377088;
    __hip_bfloat16* wt_cs = ws + (size_t)28966912;
    __hip_bfloat16* wh1   = ws + (size_t)29556736;
    __hip_bfloat16* xt_k  = ws + (size_t)29622272;
    __hip_bfloat16* xt_s  = ws + (size_t)31227904;
    __hip_bfloat16* feat  = ws + (size_t)29622272;

    (void)in_sizes; (void)n_in; (void)out_size; (void)ws_size;

    // 1) merged pre-passes (wt transposes, w_h1 cast, NHWC converts)
    prepass<<<4992, 256, 0, stream>>>(w_ck, wt_ck, w_cs, wt_cs, w_h1, wh1,
                                      kernel, xt_k, search, xt_s);

    // 2) both convs in one dispatch: search (421 tiles) + kernel branch (13)
    conv_both<<<434, 512, 0, stream>>>(xt_s, wt_cs, g2, b2, m2, v2, y2,
                                       xt_k, wt_ck, g1, b1, m1, v1, y1);

    // 3) depthwise xcorr -> feat NHWC
    xcorr_dw_nhwc2<<<dim3(25, 128), 128, 0, stream>>>(y2, y1, feat);

    // 4) fused head (layer1 MFMA + BN + ReLU + layer2 dot) -> out
    head_fused8<<<313, 512, 0, stream>>>(feat, wh1, g3, b3, m3, v3, w_h2, b_h2, out);
}

// Round 13
// 302.098 us; speedup vs baseline: 1.1927x; 1.0433x over previous
//
#include <hip/hip_runtime.h>
#include <hip/hip_bf16.h>

#define EPS 1e-5f

typedef __attribute__((ext_vector_type(8))) short bf16x8;
typedef __attribute__((ext_vector_type(4))) float f32x4;
typedef __attribute__((ext_vector_type(4))) unsigned short u16x4;
typedef __attribute__((ext_vector_type(8))) unsigned short u16x8;

#define WAITVM8 asm volatile("s_waitcnt vmcnt(8)" ::: "memory")
#define WAITVM4 asm volatile("s_waitcnt vmcnt(4)" ::: "memory")
#define WAITVM0 asm volatile("s_waitcnt vmcnt(0)" ::: "memory")
#define BAR()   __builtin_amdgcn_s_barrier()

// ---- async global->LDS, 16B per lane, linear dest (wave-uniform base + lane*16)
__device__ __forceinline__ void gld_lds16(const void* g, void* l) {
    __builtin_amdgcn_global_load_lds(
        (const __attribute__((address_space(1))) unsigned int*)g,
        (__attribute__((address_space(3))) unsigned int*)l, 16, 0, 0);
}

// ---- GEMM step macros (R9 schedule: 1 barrier + 1 counted vm-wait per K32).
#define RD8(RA, RB, SEL) do {                                                  \
    const int _b = (SEL) * 8192;                                               \
    _Pragma("unroll") for (int _i = 0; _i < 4; ++_i)                           \
        RA[_i] = *reinterpret_cast<const bf16x8*>(&lA[_b + aoff + _i * 512]);  \
    _Pragma("unroll") for (int _j = 0; _j < 4; ++_j)                           \
        RB[_j] = *reinterpret_cast<const bf16x8*>(&lB[_b + boff + _j * 512]);  \
} while (0)

#define RD4(RA4, SEL) do {                                                     \
    const int _b = (SEL) * 8192;                                               \
    _Pragma("unroll") for (int _i = 0; _i < 4; ++_i)                           \
        RA4[_i] = *reinterpret_cast<const bf16x8*>(                            \
            &lA[_b + aoff + (_i + 4) * 512]);                                  \
} while (0)

#define MFQ(RA, RB, I0) do {                                                   \
    _Pragma("unroll") for (int _i = 0; _i < 4; ++_i)                           \
    _Pragma("unroll") for (int _j = 0; _j < 4; ++_j)                           \
        acc[(I0) + _i][_j] = __builtin_amdgcn_mfma_f32_16x16x32_bf16(          \
            RA[_i], RB[_j], acc[(I0) + _i][_j], 0, 0, 0);                      \
} while (0)

#define STEP(CA0, CA4, CB, NA0, NB, SELT, STAGE_STMT, WAIT_STMT, DORD) do {    \
    RD4(CA4, (SELT));                                                          \
    STAGE_STMT;                                                                \
    __builtin_amdgcn_s_setprio(1); MFQ(CA0, CB, 0);                            \
    __builtin_amdgcn_s_setprio(0);                                             \
    WAIT_STMT;                                                                 \
    BAR();                                                                     \
    if (DORD) RD8(NA0, NB, ((SELT) + 1) & 3);                                  \
    __builtin_amdgcn_s_setprio(1); MFQ(CA4, CB, 4);                            \
    __builtin_amdgcn_s_setprio(0);                                             \
} while (0)

// =============== conv3x3 implicit-GEMM device body (R9 schedule) =============
template<int HIN, int WIN, int NTOT>
__device__ __forceinline__ void conv_dev(
    int bid, int tid,
    __hip_bfloat16* lA, __hip_bfloat16* lB,
    const __hip_bfloat16* __restrict__ xt,  // [B][HIN][WIN][256]
    const __hip_bfloat16* __restrict__ wt,  // [256][9][256]
    const float* __restrict__ g, const float* __restrict__ bb,
    const float* __restrict__ mm_, const float* __restrict__ vv,
    __hip_bfloat16* __restrict__ y)         // NHWC: [NTOT][256]
{
    constexpr int HOUT = HIN - 2, WOUT = WIN - 2, POUT = HOUT * WOUT;
    const int n0  = bid * 256;
    const int wid = tid >> 6, lane = tid & 63;
    const int wr = wid >> 2, wc = wid & 3;

    const int arow = tid >> 2;                       // 0..127
    const int seg  = (tid & 3) ^ ((tid >> 3) & 3);   // inverse slot-swizzle

    const size_t wbase0 = (size_t)arow * 2304 + seg * 8;
    const size_t wbase1 = (size_t)(arow + 128) * 2304 + seg * 8;

    int nr0 = n0 + arow;       if (nr0 > NTOT - 1) nr0 = NTOT - 1;
    int nr1 = n0 + arow + 128; if (nr1 > NTOT - 1) nr1 = NTOT - 1;
    int b0 = nr0 / POUT, p0 = nr0 % POUT, oy0 = p0 / WOUT, ox0 = p0 % WOUT;
    int b1 = nr1 / POUT, p1 = nr1 % POUT, oy1 = p1 / WOUT, ox1 = p1 % WOUT;
    const size_t xbase0 = (((size_t)b0 * HIN + oy0) * WIN + ox0) * 256 + seg * 8;
    const size_t xbase1 = (((size_t)b1 * HIN + oy1) * WIN + ox1) * 256 + seg * 8;

    auto stage = [&](int c0, int j, int sel) {
        char* a0 = (char*)lA + sel * 16384 + wid * 1024;
        char* b0p = (char*)lB + sel * 16384 + wid * 1024;
        const int woff = j * 256 + c0;
        gld_lds16(wt + wbase0 + woff, a0);
        gld_lds16(wt + wbase1 + woff, a0 + 8192);
        const int xoff = ((j / 3) * WIN + (j % 3)) * 256 + c0;
        gld_lds16(xt + xbase0 + xoff, b0p);
        gld_lds16(xt + xbase1 + xoff, b0p + 8192);
    };

    f32x4 acc[8][4];
#pragma unroll
    for (int i = 0; i < 8; ++i)
#pragma unroll
        for (int j = 0; j < 4; ++j)
            acc[i][j] = f32x4{0.f, 0.f, 0.f, 0.f};

    const int l15 = lane & 15, l16 = lane >> 4;
    const int slot = l16 ^ ((l15 >> 1) & 3);
    const int aoff = (wr * 128 + l15) * 32 + slot * 8;
    const int boff = (wc * 64  + l15) * 32 + slot * 8;

    bf16x8 pA0[4], pA4[4], pB[4], qA0[4], qA4[4], qB[4];

    stage(0, 0, 0); stage(0, 1, 1); stage(0, 2, 2);
    int js = 3, c0s = 0;  // stage cursor for step t+3
    WAITVM8; BAR();
    RD8(pA0, pB, 0);

#define ADVC do { ++js; if (js == 9) { js = 0; c0s += 32; } } while (0)
    for (int tt = 0; tt < 17; ++tt) {
        STEP(pA0, pA4, pB, qA0, qB, 0, stage(c0s, js, 3), WAITVM8, true); ADVC;
        STEP(qA0, qA4, qB, pA0, pB, 1, stage(c0s, js, 0), WAITVM8, true); ADVC;
        STEP(pA0, pA4, pB, qA0, qB, 2, stage(c0s, js, 1), WAITVM8, true); ADVC;
        STEP(qA0, qA4, qB, pA0, pB, 3, stage(c0s, js, 2), WAITVM8, true); ADVC;
    }
    STEP(pA0, pA4, pB, qA0, qB, 0, stage(c0s, js, 3), WAITVM8, true);
    STEP(qA0, qA4, qB, pA0, pB, 1, (void)0,           WAITVM4, true);
    STEP(pA0, pA4, pB, qA0, qB, 2, (void)0,           WAITVM0, true);
    STEP(qA0, qA4, qB, pA0, pB, 3, (void)0,           (void)0, false);
#undef ADVC

#pragma unroll
    for (int i = 0; i < 8; ++i) {
        const int co_b = wr * 128 + i * 16 + l16 * 4;
        float sc[4], sh[4];
#pragma unroll
        for (int r = 0; r < 4; ++r) {
            sc[r] = g[co_b + r] * rsqrtf(vv[co_b + r] + EPS);
            sh[r] = bb[co_b + r] - mm_[co_b + r] * sc[r];
        }
#pragma unroll
        for (int jj = 0; jj < 4; ++jj) {
            const int n = n0 + wc * 64 + jj * 16 + l15;
            if (n < NTOT) {
                u16x4 o;
#pragma unroll
                for (int r = 0; r < 4; ++r) {
                    const float v = fmaxf(fmaf(acc[i][jj][r], sc[r], sh[r]), 0.f);
                    __hip_bfloat16 hv = __float2bfloat16(v);
                    o[r] = *reinterpret_cast<unsigned short*>(&hv);
                }
                *reinterpret_cast<u16x4*>(&y[(size_t)n * 256 + co_b]) = o;
            }
        }
    }
}

// ---------------- conv_both: search blocks 0..420, kernel blocks 421..433 ----
__global__ __launch_bounds__(512, 2) void conv_both(
    const __hip_bfloat16* __restrict__ xt_s, const __hip_bfloat16* __restrict__ wt_cs,
    const float* __restrict__ g2, const float* __restrict__ b2,
    const float* __restrict__ m2, const float* __restrict__ v2,
    __hip_bfloat16* __restrict__ y2,
    const __hip_bfloat16* __restrict__ xt_k, const __hip_bfloat16* __restrict__ wt_ck,
    const float* __restrict__ g1, const float* __restrict__ b1,
    const float* __restrict__ m1, const float* __restrict__ v1,
    __hip_bfloat16* __restrict__ y1)
{
    __shared__ __align__(16) __hip_bfloat16 lA[4 * 8192];
    __shared__ __align__(16) __hip_bfloat16 lB[4 * 8192];
    if (blockIdx.x < 421)
        conv_dev<31, 31, 107648>(blockIdx.x, threadIdx.x, lA, lB,
                                 xt_s, wt_cs, g2, b2, m2, v2, y2);
    else
        conv_dev<7, 7, 3200>(blockIdx.x - 421, threadIdx.x, lA, lB,
                             xt_k, wt_ck, g1, b1, m1, v1, y1);
}

// =============== merged pre-pass kernel ======================================
__device__ __forceinline__ void nhwc_body(
    const float* __restrict__ x, __hip_bfloat16* __restrict__ xt, int P,
    int bx, int b, float* t /* [256*33] */)
{
    const int p0 = bx * 32;
    const float* xb = x + (size_t)b * 256 * P;
    const int pl = threadIdx.x & 31, cg = threadIdx.x >> 5;
#pragma unroll
    for (int it = 0; it < 32; ++it) {
        int c = cg + it * 8, p = p0 + pl;
        t[c * 33 + pl] = (p < P) ? xb[(size_t)c * P + p] : 0.f;
    }
    __syncthreads();
    const int p = threadIdx.x >> 3, l8 = threadIdx.x & 7;
    if (p0 + p < P) {
        __hip_bfloat16* xo = xt + ((size_t)b * P + p0 + p) * 256;
#pragma unroll
        for (int j = 0; j < 4; ++j) {
            const int c0 = j * 64 + l8 * 8;
            u16x8 o;
#pragma unroll
            for (int r = 0; r < 8; ++r) {
                __hip_bfloat16 hv = __float2bfloat16(t[(c0 + r) * 33 + p]);
                o[r] = *reinterpret_cast<unsigned short*>(&hv);
            }
            *reinterpret_cast<u16x8*>(&xo[c0]) = o;
        }
    }
}

__global__ __launch_bounds__(256) void prepass(
    const float* __restrict__ w_ck, __hip_bfloat16* __restrict__ wt_ck,
    const float* __restrict__ w_cs, __hip_bfloat16* __restrict__ wt_cs,
    const float* __restrict__ w_h1, __hip_bfloat16* __restrict__ wh1,
    const float* __restrict__ kernel, __hip_bfloat16* __restrict__ xt_k,
    const float* __restrict__ search, __hip_bfloat16* __restrict__ xt_s)
{
    __shared__ float t[256 * 33];
    const int bid = blockIdx.x;
    if (bid < 512) {
        const float* w = (bid < 256) ? w_ck : w_cs;
        __hip_bfloat16* wt = (bid < 256) ? wt_ck : wt_cs;
        const int co = bid & 255, ci = threadIdx.x;
        const float* wp = w + (size_t)co * 2304 + (size_t)ci * 9;
        __hip_bfloat16* wo = wt + (size_t)co * 2304 + ci;
#pragma unroll
        for (int j = 0; j < 9; ++j)
            wo[(size_t)j * 256] = __float2bfloat16(wp[j]);
    } else if (bid < 768) {
        const int i = (bid - 512) * 256 + threadIdx.x;
        wh1[i] = __float2bfloat16(w_h1[i]);
    } else if (bid < 1024) {
        const int idx = bid - 768;
        nhwc_body(kernel, xt_k, 49, idx & 1, idx >> 1, t);
    } else {
        const int idx = bid - 1024;
        nhwc_body(search, xt_s, 961, idx % 31, idx / 31, t);
    }
}

// ---------------- depthwise xcorr 5x5, strip version --------------------------
// Block = (strip, b); strip covers py0..py0+4 (5 output rows); 256 thr = ch.
// Reads 9 input rows ONCE (rolling), produces 5 output rows: read
// amplification 1.8x vs 5x for the per-row version. Fully unrolled r-loop so
// every acc index is compile-time (no scratch).
__global__ __launch_bounds__(256) void xcorr_strip(
    const __hip_bfloat16* __restrict__ s,  // [B][841][256]
    const __hip_bfloat16* __restrict__ k,  // [B][25][256]
    __hip_bfloat16* __restrict__ f)        // [B][625][256]
{
    const int st = blockIdx.x, b = blockIdx.y, c = threadIdx.x;
    const int py0 = st * 5;
    const __hip_bfloat16* sp = s + (size_t)b * 841 * 256 + c;
    const __hip_bfloat16* kp = k + (size_t)b * 25 * 256 + c;

    float kv[25];
#pragma unroll
    for (int i = 0; i < 25; ++i)
        kv[i] = __bfloat162float(kp[(size_t)i * 256]);

    float acc[5][25];
#pragma unroll
    for (int p = 0; p < 5; ++p)
#pragma unroll
        for (int px = 0; px < 25; ++px) acc[p][px] = 0.f;

#pragma unroll
    for (int r = 0; r < 9; ++r) {           // absolute row py0 + r
        float srow[29];
        const __hip_bfloat16* srp = sp + (size_t)(py0 + r) * 29 * 256;
#pragma unroll
        for (int rx = 0; rx < 29; ++rx)
            srow[rx] = __bfloat162float(srp[(size_t)rx * 256]);
#pragma unroll
        for (int p = 0; p < 5; ++p) {
            if (r >= p && r - p <= 4) {     // constant-folds after unroll
                const int ky = r - p;
#pragma unroll
                for (int kx = 0; kx < 5; ++kx) {
                    const float kvv = kv[ky * 5 + kx];
#pragma unroll
                    for (int px = 0; px < 25; ++px)
                        acc[p][px] = fmaf(srow[px + kx], kvv, acc[p][px]);
                }
            }
        }
    }

#pragma unroll
    for (int p = 0; p < 5; ++p) {
        __hip_bfloat16* fp = f + ((size_t)b * 625 + (size_t)(py0 + p) * 25) * 256 + c;
#pragma unroll
        for (int px = 0; px < 25; ++px)
            fp[(size_t)px * 256] = __float2bfloat16(acc[p][px]);
    }
}

// ---------------- head: 1x1 conv (MFMA) + BN + ReLU + 1x1 conv (256->10) -----
__global__ __launch_bounds__(512) void head_fused8(
    const __hip_bfloat16* __restrict__ f,   // [N][256]
    const __hip_bfloat16* __restrict__ w1,  // [256][256] bf16
    const float* __restrict__ g, const float* __restrict__ bb,
    const float* __restrict__ mm_, const float* __restrict__ vv,
    const float* __restrict__ w2,           // [10][256]
    const float* __restrict__ b2v,          // [10]
    float* __restrict__ out)                // [B][10][25][25]
{
    constexpr int NTOT = 80000;
    const int n0  = blockIdx.x * 256;
    const int tid = threadIdx.x;
    const int wid = tid >> 6, lane = tid & 63;
    const int wr = wid >> 2, wc = wid & 3;

    __shared__ __align__(16) __hip_bfloat16 lA[4 * 8192];
    __shared__ __align__(16) __hip_bfloat16 lB[4 * 8192];

    const int arow = tid >> 2;
    const int seg  = (tid & 3) ^ ((tid >> 3) & 3);

    const size_t wbase0 = (size_t)arow * 256 + seg * 8;
    const size_t wbase1 = (size_t)(arow + 128) * 256 + seg * 8;
    int nr0 = n0 + arow;       if (nr0 > NTOT - 1) nr0 = NTOT - 1;
    int nr1 = n0 + arow + 128; if (nr1 > NTOT - 1) nr1 = NTOT - 1;
    const size_t xbase0 = (size_t)nr0 * 256 + seg * 8;
    const size_t xbase1 = (size_t)nr1 * 256 + seg * 8;

    auto stage = [&](int c0, int sel) {
        char* a0 = (char*)lA + sel * 16384 + wid * 1024;
        char* b0p = (char*)lB + sel * 16384 + wid * 1024;
        gld_lds16(w1 + wbase0 + c0, a0);
        gld_lds16(w1 + wbase1 + c0, a0 + 8192);
        gld_lds16(f + xbase0 + c0, b0p);
        gld_lds16(f + xbase1 + c0, b0p + 8192);
    };

    f32x4 acc[8][4];
#pragma unroll
    for (int i = 0; i < 8; ++i)
#pragma unroll
        for (int j = 0; j < 4; ++j)
            acc[i][j] = f32x4{0.f, 0.f, 0.f, 0.f};

    const int l15 = lane & 15, l16 = lane >> 4;
    const int slot = l16 ^ ((l15 >> 1) & 3);
    const int aoff = (wr * 128 + l15) * 32 + slot * 8;
    const int boff = (wc * 64  + l15) * 32 + slot * 8;

    bf16x8 pA0[4], pA4[4], pB[4], qA0[4], qA4[4], qB[4];

    stage(0, 0); stage(32, 1); stage(64, 2);
    WAITVM8; BAR();
    RD8(pA0, pB, 0);

    STEP(pA0, pA4, pB, qA0, qB, 0, stage(96, 3),  WAITVM8, true);   // t=0
    STEP(qA0, qA4, qB, pA0, pB, 1, stage(128, 0), WAITVM8, true);   // t=1
    STEP(pA0, pA4, pB, qA0, qB, 2, stage(160, 1), WAITVM8, true);   // t=2
    STEP(qA0, qA4, qB, pA0, pB, 3, stage(192, 2), WAITVM8, true);   // t=3
    STEP(pA0, pA4, pB, qA0, qB, 0, stage(224, 3), WAITVM8, true);   // t=4
    STEP(qA0, qA4, qB, pA0, pB, 1, (void)0,       WAITVM4, true);   // t=5
    STEP(pA0, pA4, pB, qA0, qB, 2, (void)0,       WAITVM0, true);   // t=6
    STEP(qA0, qA4, qB, pA0, pB, 3, (void)0,       (void)0, false);  // t=7

    // ---- fused layer-2 epilogue ----
    __syncthreads();                 // all waves done reading lA/lB
    float* lw   = (float*)lA;        // [10][256] w2, then [10] b2
    float* lred = (float*)lB;        // [4 wc][4 jj][16 l15][10 o] wr=0 partials
    for (int t = tid; t < 2560; t += 512) lw[t] = w2[t];
    if (tid < 10) lw[2560 + tid] = b2v[tid];
    __syncthreads();

    float p[4][10];
#pragma unroll
    for (int jj = 0; jj < 4; ++jj)
#pragma unroll
        for (int o = 0; o < 10; ++o) p[jj][o] = 0.f;

#pragma unroll
    for (int i = 0; i < 8; ++i) {
        const int co_b = wr * 128 + i * 16 + l16 * 4;
        float sc[4], sh[4];
#pragma unroll
        for (int r = 0; r < 4; ++r) {
            sc[r] = g[co_b + r] * rsqrtf(vv[co_b + r] + EPS);
            sh[r] = bb[co_b + r] - mm_[co_b + r] * sc[r];
        }
        float w4[10][4];
#pragma unroll
        for (int o = 0; o < 10; ++o) {
            f32x4 wv = *reinterpret_cast<const f32x4*>(&lw[o * 256 + co_b]);
#pragma unroll
            for (int r = 0; r < 4; ++r) w4[o][r] = wv[r];
        }
#pragma unroll
        for (int jj = 0; jj < 4; ++jj) {
            float hv[4];
#pragma unroll
            for (int r = 0; r < 4; ++r)
                hv[r] = fmaxf(fmaf(acc[i][jj][r], sc[r], sh[r]), 0.f);
#pragma unroll
            for (int o = 0; o < 10; ++o)
#pragma unroll
                for (int r = 0; r < 4; ++r)
                    p[jj][o] = fmaf(hv[r], w4[o][r], p[jj][o]);
        }
    }

    // reduce across l16 groups (co spread over 4 lanes at stride 16)
#pragma unroll
    for (int jj = 0; jj < 4; ++jj)
#pragma unroll
        for (int o = 0; o < 10; ++o) {
            float v = p[jj][o];
            v += __shfl_xor(v, 16, 64);
            v += __shfl_xor(v, 32, 64);
            p[jj][o] = v;
        }

    // cross-wave (wr) reduce via LDS
    if (wr == 0 && l16 == 0) {
#pragma unroll
        for (int jj = 0; jj < 4; ++jj)
#pragma unroll
            for (int o = 0; o < 10; ++o)
                lred[((wc * 4 + jj) * 16 + l15) * 10 + o] = p[jj][o];
    }
    __syncthreads();
    if (wr == 1) {
#pragma unroll
        for (int jj = 0; jj < 4; ++jj) {
            const int n = n0 + wc * 64 + jj * 16 + l15;
            if (n < NTOT) {
                const int bi = n / 625, pp = n % 625;
#pragma unroll
                for (int t = 0; t < 3; ++t) {
                    const int o = l16 + 4 * t;
                    if (o < 10) {
                        float v = p[jj][o]
                                + lred[((wc * 4 + jj) * 16 + l15) * 10 + o]
                                + lw[2560 + o];
                        out[((size_t)bi * 10 + o) * 625 + pp] = v;
                    }
                }
            }
        }
    }
}

extern "C" void kernel_launch(void* const* d_in, const int* in_sizes, int n_in,
                              void* d_out, int out_size, void* d_ws, size_t ws_size,
                              hipStream_t stream) {
    const float* kernel = (const float*)d_in[0];   // [128,256,7,7]
    const float* search = (const float*)d_in[1];   // [128,256,31,31]
    const float* w_ck   = (const float*)d_in[2];
    const float* g1 = (const float*)d_in[3];
    const float* b1 = (const float*)d_in[4];
    const float* m1 = (const float*)d_in[5];
    const float* v1 = (const float*)d_in[6];
    const float* w_cs   = (const float*)d_in[7];
    const float* g2 = (const float*)d_in[8];
    const float* b2 = (const float*)d_in[9];
    const float* m2 = (const float*)d_in[10];
    const float* v2 = (const float*)d_in[11];
    const float* w_h1   = (const float*)d_in[12];
    const float* g3 = (const float*)d_in[13];
    const float* b3 = (const float*)d_in[14];
    const float* m3 = (const float*)d_in[15];
    const float* v3 = (const float*)d_in[16];
    const float* w_h2   = (const float*)d_in[17];
    const float* b_h2   = (const float*)d_in[18];

    float* out = (float*)d_out;

    __hip_bfloat16* ws = (__hip_bfloat16*)d_ws;
    __hip_bfloat16* y1    = ws;
    __hip_bfloat16* y2    = ws + (size_t)819200;
    __hip_bfloat16* wt_ck = ws + (size_t)28377088;
    __hip_bfloat16* wt_cs = ws + (size_t)28966912;
    __hip_bfloat16* wh1   = ws + (size_t)29556736;
    __hip_bfloat16* xt_k  = ws + (size_t)29622272;
    __hip_bfloat16* xt_s  = ws + (size_t)31227904;
    __hip_bfloat16* feat  = ws + (size_t)29622272;

    (void)in_sizes; (void)n_in; (void)out_size; (void)ws_size;

    // 1) merged pre-passes (wt transposes, w_h1 cast, NHWC converts)
    prepass<<<4992, 256, 0, stream>>>(w_ck, wt_ck, w_cs, wt_cs, w_h1, wh1,
                                      kernel, xt_k, search, xt_s);

    // 2) both convs in one dispatch: search (421 tiles) + kernel branch (13)
    conv_both<<<434, 512, 0, stream>>>(xt_s, wt_cs, g2, b2, m2, v2, y2,
                                       xt_k, wt_ck, g1, b1, m1, v1, y1);

    // 3) depthwise xcorr -> feat NHWC (strip: 5 output rows per block)
    xcorr_strip<<<dim3(5, 128), 256, 0, stream>>>(y2, y1, feat);

    // 4) fused head (layer1 MFMA + BN + ReLU + layer2 dot) -> out
    head_fused8<<<313, 512, 0, stream>>>(feat, wh1, g3, b3, m3, v3, w_h2, b_h2, out);
}

// Round 14
// 257.829 us; speedup vs baseline: 1.3975x; 1.1717x over previous
//
#include <hip/hip_runtime.h>
#include <hip/hip_bf16.h>

#define EPS 1e-5f

typedef __attribute__((ext_vector_type(8))) short bf16x8;
typedef __attribute__((ext_vector_type(4))) float f32x4;
typedef __attribute__((ext_vector_type(4))) unsigned short u16x4;
typedef __attribute__((ext_vector_type(8))) unsigned short u16x8;

#define WAITVM8 asm volatile("s_waitcnt vmcnt(8)" ::: "memory")
#define WAITVM4 asm volatile("s_waitcnt vmcnt(4)" ::: "memory")
#define WAITVM2 asm volatile("s_waitcnt vmcnt(2)" ::: "memory")
#define WAITVM0 asm volatile("s_waitcnt vmcnt(0)" ::: "memory")
#define BAR()   __builtin_amdgcn_s_barrier()

// ---- async global->LDS, 16B per lane, linear dest (wave-uniform base + lane*16)
__device__ __forceinline__ void gld_lds16(const void* g, void* l) {
    __builtin_amdgcn_global_load_lds(
        (const __attribute__((address_space(1))) unsigned int*)g,
        (__attribute__((address_space(3))) unsigned int*)l, 16, 0, 0);
}

// ---- GEMM step macros (R9 schedule: 1 barrier + 1 counted vm-wait per K32).
#define RD8(RA, RB, SEL) do {                                                  \
    const int _b = (SEL) * 8192;                                               \
    _Pragma("unroll") for (int _i = 0; _i < 4; ++_i)                           \
        RA[_i] = *reinterpret_cast<const bf16x8*>(&lA[_b + aoff + _i * 512]);  \
    _Pragma("unroll") for (int _j = 0; _j < 4; ++_j)                           \
        RB[_j] = *reinterpret_cast<const bf16x8*>(&lB[_b + boff + _j * 512]);  \
} while (0)

#define RD4(RA4, SEL) do {                                                     \
    const int _b = (SEL) * 8192;                                               \
    _Pragma("unroll") for (int _i = 0; _i < 4; ++_i)                           \
        RA4[_i] = *reinterpret_cast<const bf16x8*>(                            \
            &lA[_b + aoff + (_i + 4) * 512]);                                  \
} while (0)

#define MFQ(RA, RB, I0) do {                                                   \
    _Pragma("unroll") for (int _i = 0; _i < 4; ++_i)                           \
    _Pragma("unroll") for (int _j = 0; _j < 4; ++_j)                           \
        acc[(I0) + _i][_j] = __builtin_amdgcn_mfma_f32_16x16x32_bf16(          \
            RA[_i], RB[_j], acc[(I0) + _i][_j], 0, 0, 0);                      \
} while (0)

#define STEP(CA0, CA4, CB, NA0, NB, SELT, STAGE_STMT, WAIT_STMT, DORD) do {    \
    RD4(CA4, (SELT));                                                          \
    STAGE_STMT;                                                                \
    __builtin_amdgcn_s_setprio(1); MFQ(CA0, CB, 0);                            \
    __builtin_amdgcn_s_setprio(0);                                             \
    WAIT_STMT;                                                                 \
    BAR();                                                                     \
    if (DORD) RD8(NA0, NB, ((SELT) + 1) & 3);                                  \
    __builtin_amdgcn_s_setprio(1); MFQ(CA4, CB, 4);                            \
    __builtin_amdgcn_s_setprio(0);                                             \
} while (0)

// =============== conv3x3 implicit-GEMM device body (R9 schedule) =============
template<int HIN, int WIN, int NTOT>
__device__ __forceinline__ void conv_dev(
    int bid, int tid,
    __hip_bfloat16* lA, __hip_bfloat16* lB,
    const __hip_bfloat16* __restrict__ xt,  // [B][HIN][WIN][256]
    const __hip_bfloat16* __restrict__ wt,  // [256][9][256]
    const float* __restrict__ g, const float* __restrict__ bb,
    const float* __restrict__ mm_, const float* __restrict__ vv,
    __hip_bfloat16* __restrict__ y)         // NHWC: [NTOT][256]
{
    constexpr int HOUT = HIN - 2, WOUT = WIN - 2, POUT = HOUT * WOUT;
    const int n0  = bid * 256;
    const int wid = tid >> 6, lane = tid & 63;
    const int wr = wid >> 2, wc = wid & 3;

    const int arow = tid >> 2;                       // 0..127
    const int seg  = (tid & 3) ^ ((tid >> 3) & 3);   // inverse slot-swizzle

    const size_t wbase0 = (size_t)arow * 2304 + seg * 8;
    const size_t wbase1 = (size_t)(arow + 128) * 2304 + seg * 8;

    int nr0 = n0 + arow;       if (nr0 > NTOT - 1) nr0 = NTOT - 1;
    int nr1 = n0 + arow + 128; if (nr1 > NTOT - 1) nr1 = NTOT - 1;
    int b0 = nr0 / POUT, p0 = nr0 % POUT, oy0 = p0 / WOUT, ox0 = p0 % WOUT;
    int b1 = nr1 / POUT, p1 = nr1 % POUT, oy1 = p1 / WOUT, ox1 = p1 % WOUT;
    const size_t xbase0 = (((size_t)b0 * HIN + oy0) * WIN + ox0) * 256 + seg * 8;
    const size_t xbase1 = (((size_t)b1 * HIN + oy1) * WIN + ox1) * 256 + seg * 8;

    auto stage = [&](int c0, int j, int sel) {
        char* a0 = (char*)lA + sel * 16384 + wid * 1024;
        char* b0p = (char*)lB + sel * 16384 + wid * 1024;
        const int woff = j * 256 + c0;
        gld_lds16(wt + wbase0 + woff, a0);
        gld_lds16(wt + wbase1 + woff, a0 + 8192);
        const int xoff = ((j / 3) * WIN + (j % 3)) * 256 + c0;
        gld_lds16(xt + xbase0 + xoff, b0p);
        gld_lds16(xt + xbase1 + xoff, b0p + 8192);
    };

    f32x4 acc[8][4];
#pragma unroll
    for (int i = 0; i < 8; ++i)
#pragma unroll
        for (int j = 0; j < 4; ++j)
            acc[i][j] = f32x4{0.f, 0.f, 0.f, 0.f};

    const int l15 = lane & 15, l16 = lane >> 4;
    const int slot = l16 ^ ((l15 >> 1) & 3);
    const int aoff = (wr * 128 + l15) * 32 + slot * 8;
    const int boff = (wc * 64  + l15) * 32 + slot * 8;

    bf16x8 pA0[4], pA4[4], pB[4], qA0[4], qA4[4], qB[4];

    stage(0, 0, 0); stage(0, 1, 1); stage(0, 2, 2);
    int js = 3, c0s = 0;  // stage cursor for step t+3
    WAITVM8; BAR();
    RD8(pA0, pB, 0);

#define ADVC do { ++js; if (js == 9) { js = 0; c0s += 32; } } while (0)
    for (int tt = 0; tt < 17; ++tt) {
        STEP(pA0, pA4, pB, qA0, qB, 0, stage(c0s, js, 3), WAITVM8, true); ADVC;
        STEP(qA0, qA4, qB, pA0, pB, 1, stage(c0s, js, 0), WAITVM8, true); ADVC;
        STEP(pA0, pA4, pB, qA0, qB, 2, stage(c0s, js, 1), WAITVM8, true); ADVC;
        STEP(qA0, qA4, qB, pA0, pB, 3, stage(c0s, js, 2), WAITVM8, true); ADVC;
    }
    STEP(pA0, pA4, pB, qA0, qB, 0, stage(c0s, js, 3), WAITVM8, true);
    STEP(qA0, qA4, qB, pA0, pB, 1, (void)0,           WAITVM4, true);
    STEP(pA0, pA4, pB, qA0, qB, 2, (void)0,           WAITVM0, true);
    STEP(qA0, qA4, qB, pA0, pB, 3, (void)0,           (void)0, false);
#undef ADVC

#pragma unroll
    for (int i = 0; i < 8; ++i) {
        const int co_b = wr * 128 + i * 16 + l16 * 4;
        float sc[4], sh[4];
#pragma unroll
        for (int r = 0; r < 4; ++r) {
            sc[r] = g[co_b + r] * rsqrtf(vv[co_b + r] + EPS);
            sh[r] = bb[co_b + r] - mm_[co_b + r] * sc[r];
        }
#pragma unroll
        for (int jj = 0; jj < 4; ++jj) {
            const int n = n0 + wc * 64 + jj * 16 + l15;
            if (n < NTOT) {
                u16x4 o;
#pragma unroll
                for (int r = 0; r < 4; ++r) {
                    const float v = fmaxf(fmaf(acc[i][jj][r], sc[r], sh[r]), 0.f);
                    __hip_bfloat16 hv = __float2bfloat16(v);
                    o[r] = *reinterpret_cast<unsigned short*>(&hv);
                }
                *reinterpret_cast<u16x4*>(&y[(size_t)n * 256 + co_b]) = o;
            }
        }
    }
}

// ---------------- conv_both: search blocks 0..420, kernel blocks 421..433 ----
__global__ __launch_bounds__(512, 2) void conv_both(
    const __hip_bfloat16* __restrict__ xt_s, const __hip_bfloat16* __restrict__ wt_cs,
    const float* __restrict__ g2, const float* __restrict__ b2,
    const float* __restrict__ m2, const float* __restrict__ v2,
    __hip_bfloat16* __restrict__ y2,
    const __hip_bfloat16* __restrict__ xt_k, const __hip_bfloat16* __restrict__ wt_ck,
    const float* __restrict__ g1, const float* __restrict__ b1,
    const float* __restrict__ m1, const float* __restrict__ v1,
    __hip_bfloat16* __restrict__ y1)
{
    __shared__ __align__(16) __hip_bfloat16 lA[4 * 8192];
    __shared__ __align__(16) __hip_bfloat16 lB[4 * 8192];
    if (blockIdx.x < 421)
        conv_dev<31, 31, 107648>(blockIdx.x, threadIdx.x, lA, lB,
                                 xt_s, wt_cs, g2, b2, m2, v2, y2);
    else
        conv_dev<7, 7, 3200>(blockIdx.x - 421, threadIdx.x, lA, lB,
                             xt_k, wt_ck, g1, b1, m1, v1, y1);
}

// =============== merged pre-pass kernel ======================================
__device__ __forceinline__ void nhwc_body(
    const float* __restrict__ x, __hip_bfloat16* __restrict__ xt, int P,
    int bx, int b, float* t /* [256*33] */)
{
    const int p0 = bx * 32;
    const float* xb = x + (size_t)b * 256 * P;
    const int pl = threadIdx.x & 31, cg = threadIdx.x >> 5;
#pragma unroll
    for (int it = 0; it < 32; ++it) {
        int c = cg + it * 8, p = p0 + pl;
        t[c * 33 + pl] = (p < P) ? xb[(size_t)c * P + p] : 0.f;
    }
    __syncthreads();
    const int p = threadIdx.x >> 3, l8 = threadIdx.x & 7;
    if (p0 + p < P) {
        __hip_bfloat16* xo = xt + ((size_t)b * P + p0 + p) * 256;
#pragma unroll
        for (int j = 0; j < 4; ++j) {
            const int c0 = j * 64 + l8 * 8;
            u16x8 o;
#pragma unroll
            for (int r = 0; r < 8; ++r) {
                __hip_bfloat16 hv = __float2bfloat16(t[(c0 + r) * 33 + p]);
                o[r] = *reinterpret_cast<unsigned short*>(&hv);
            }
            *reinterpret_cast<u16x8*>(&xo[c0]) = o;
        }
    }
}

__global__ __launch_bounds__(256) void prepass(
    const float* __restrict__ w_ck, __hip_bfloat16* __restrict__ wt_ck,
    const float* __restrict__ w_cs, __hip_bfloat16* __restrict__ wt_cs,
    const float* __restrict__ w_h1, __hip_bfloat16* __restrict__ wh1,
    const float* __restrict__ kernel, __hip_bfloat16* __restrict__ xt_k,
    const float* __restrict__ search, __hip_bfloat16* __restrict__ xt_s)
{
    __shared__ float t[256 * 33];
    const int bid = blockIdx.x;
    if (bid < 512) {
        const float* w = (bid < 256) ? w_ck : w_cs;
        __hip_bfloat16* wt = (bid < 256) ? wt_ck : wt_cs;
        const int co = bid & 255, ci = threadIdx.x;
        const float* wp = w + (size_t)co * 2304 + (size_t)ci * 9;
        __hip_bfloat16* wo = wt + (size_t)co * 2304 + ci;
#pragma unroll
        for (int j = 0; j < 9; ++j)
            wo[(size_t)j * 256] = __float2bfloat16(wp[j]);
    } else if (bid < 768) {
        const int i = (bid - 512) * 256 + threadIdx.x;
        wh1[i] = __float2bfloat16(w_h1[i]);
    } else if (bid < 1024) {
        const int idx = bid - 768;
        nhwc_body(kernel, xt_k, 49, idx & 1, idx >> 1, t);
    } else {
        const int idx = bid - 1024;
        nhwc_body(search, xt_s, 961, idx % 31, idx / 31, t);
    }
}

// ======= fused xcorr (5-row strip) + head layer1 MFMA + BN/ReLU + layer2 =====
// Block = (strip st, batch b), 512 thr = 8 waves. Phase 1: waves 0-3 compute
// feat rows p=0..2, waves 4-7 rows p=3..4 (per-channel 5x5 xcorr), written to
// LDS featL[128][264] bf16 (pad 8 elems -> odd 16B-slot row stride: reading a
// column slice across rows is conflict-free, no swizzle). Phase 2: head GEMM
// M=256(co) x N=128(px,3 pad) x K=256 -- A=w1 staged (3 bufs, depth-2, counted
// vmcnt(2), conv's proven seg-swizzle), B straight from featL. Phase 3: R11's
// fused BN+ReLU+layer-2 epilogue, f32 store to out. No feat HBM round-trip.
__global__ __launch_bounds__(512) void xcorr_head(
    const __hip_bfloat16* __restrict__ s,   // y2 [B][841][256]
    const __hip_bfloat16* __restrict__ k,   // y1 [B][25][256]
    const __hip_bfloat16* __restrict__ w1,  // [256][256] bf16
    const float* __restrict__ g, const float* __restrict__ bb,
    const float* __restrict__ mm_, const float* __restrict__ vv,
    const float* __restrict__ w2,           // [10][256]
    const float* __restrict__ b2v,          // [10]
    float* __restrict__ out)                // [B][10][25][25]
{
    const int st = blockIdx.x, b = blockIdx.y;
    const int py0 = st * 5;
    const int tid = threadIdx.x;

    __shared__ __align__(16) __hip_bfloat16 featL[128 * 264];  // 67.6 KB
    __shared__ __align__(16) __hip_bfloat16 lA[3 * 8192];      // 48 KB

    // ---------------- phase 1: xcorr -> featL ----------------
    {
        const int c = tid & 255, h = tid >> 8;   // wave-uniform h
        const __hip_bfloat16* sp = s + (size_t)b * 841 * 256 + c;
        const __hip_bfloat16* kp = k + (size_t)b * 25 * 256 + c;
        float kv[25];
#pragma unroll
        for (int i = 0; i < 25; ++i)
            kv[i] = __bfloat162float(kp[(size_t)i * 256]);

        if (h == 0) {          // p = 0..2, rows py0 .. py0+6
            float acc3[3][25];
#pragma unroll
            for (int p = 0; p < 3; ++p)
#pragma unroll
                for (int px = 0; px < 25; ++px) acc3[p][px] = 0.f;
#pragma unroll
            for (int r = 0; r < 7; ++r) {
                float srow[29];
                const __hip_bfloat16* srp = sp + (size_t)(py0 + r) * 29 * 256;
#pragma unroll
                for (int rx = 0; rx < 29; ++rx)
                    srow[rx] = __bfloat162float(srp[(size_t)rx * 256]);
#pragma unroll
                for (int p = 0; p < 3; ++p) {
                    if (r >= p && r - p <= 4) {
                        const int ky = r - p;
#pragma unroll
                        for (int kx = 0; kx < 5; ++kx) {
                            const float kvv = kv[ky * 5 + kx];
#pragma unroll
                            for (int px = 0; px < 25; ++px)
                                acc3[p][px] = fmaf(srow[px + kx], kvv, acc3[p][px]);
                        }
                    }
                }
            }
#pragma unroll
            for (int p = 0; p < 3; ++p)
#pragma unroll
                for (int px = 0; px < 25; ++px)
                    featL[(p * 25 + px) * 264 + c] = __float2bfloat16(acc3[p][px]);
        } else {               // p = 3..4, rows py0+3 .. py0+8
            float acc2[2][25];
#pragma unroll
            for (int p = 0; p < 2; ++p)
#pragma unroll
                for (int px = 0; px < 25; ++px) acc2[p][px] = 0.f;
#pragma unroll
            for (int r = 3; r < 9; ++r) {
                float srow[29];
                const __hip_bfloat16* srp = sp + (size_t)(py0 + r) * 29 * 256;
#pragma unroll
                for (int rx = 0; rx < 29; ++rx)
                    srow[rx] = __bfloat162float(srp[(size_t)rx * 256]);
#pragma unroll
                for (int p = 3; p < 5; ++p) {
                    if (r >= p && r - p <= 4) {
                        const int ky = r - p;
#pragma unroll
                        for (int kx = 0; kx < 5; ++kx) {
                            const float kvv = kv[ky * 5 + kx];
#pragma unroll
                            for (int px = 0; px < 25; ++px)
                                acc2[p - 3][px] = fmaf(srow[px + kx], kvv, acc2[p - 3][px]);
                        }
                    }
                }
            }
#pragma unroll
            for (int p = 0; p < 2; ++p)
#pragma unroll
                for (int px = 0; px < 25; ++px)
                    featL[((p + 3) * 25 + px) * 264 + c] = __float2bfloat16(acc2[p][px]);
        }
    }
    __syncthreads();

    // ---------------- phase 2: head GEMM ----------------
    const int wid = tid >> 6, lane = tid & 63;
    const int wr = wid >> 2, wc = wid & 3;       // wave tile 128co x 32px
    const int l15 = lane & 15, l16 = lane >> 4;
    const int seg  = (lane & 3) ^ ((lane >> 3) & 3);
    const int slot = l16 ^ ((l15 >> 1) & 3);
    const int aoff = (wr * 128 + l15) * 32 + slot * 8;

    auto stageA = [&](int c0, int sel) {
        char* dst = (char*)lA + sel * 16384 + wid * 2048;  // 32 rows x 64B/wave
        const size_t r0 = (size_t)(wid * 32 + (lane >> 2)) * 256;
        gld_lds16(w1 + r0 + c0 + seg * 8, dst);
        gld_lds16(w1 + r0 + 16 * 256 + c0 + seg * 8, dst + 1024);
    };

    f32x4 acc[8][2];
#pragma unroll
    for (int i = 0; i < 8; ++i) {
        acc[i][0] = f32x4{0.f, 0.f, 0.f, 0.f};
        acc[i][1] = f32x4{0.f, 0.f, 0.f, 0.f};
    }

#define RDH(AF, BF, SEL, C0) do {                                              \
    const int _b = (SEL) * 8192;                                               \
    _Pragma("unroll") for (int _i = 0; _i < 8; ++_i)                           \
        AF[_i] = *reinterpret_cast<const bf16x8*>(&lA[_b + aoff + _i * 512]);  \
    _Pragma("unroll") for (int _j = 0; _j < 2; ++_j)                           \
        BF[_j] = *reinterpret_cast<const bf16x8*>(                             \
            &featL[(wc * 32 + _j * 16 + l15) * 264 + (C0) + l16 * 8]);         \
} while (0)

#define MFH(AF, BF) do {                                                       \
    __builtin_amdgcn_s_setprio(1);                                             \
    _Pragma("unroll") for (int _i = 0; _i < 8; ++_i)                           \
    _Pragma("unroll") for (int _j = 0; _j < 2; ++_j)                           \
        acc[_i][_j] = __builtin_amdgcn_mfma_f32_16x16x32_bf16(                 \
            AF[_i], BF[_j], acc[_i][_j], 0, 0, 0);                             \
    __builtin_amdgcn_s_setprio(0);                                             \
} while (0)

    {
        bf16x8 af[8], bf[2];
        stageA(0, 0); stageA(32, 1);
        WAITVM2; BAR();
        RDH(af, bf, 0, 0);   stageA(64, 2);  MFH(af, bf);   // t=0
        WAITVM2; BAR();
        RDH(af, bf, 1, 32);  stageA(96, 0);  MFH(af, bf);   // t=1
        WAITVM2; BAR();
        RDH(af, bf, 2, 64);  stageA(128, 1); MFH(af, bf);   // t=2
        WAITVM2; BAR();
        RDH(af, bf, 0, 96);  stageA(160, 2); MFH(af, bf);   // t=3
        WAITVM2; BAR();
        RDH(af, bf, 1, 128); stageA(192, 0); MFH(af, bf);   // t=4
        WAITVM2; BAR();
        RDH(af, bf, 2, 160); stageA(224, 1); MFH(af, bf);   // t=5
        WAITVM2; BAR();
        RDH(af, bf, 0, 192);                 MFH(af, bf);   // t=6
        WAITVM0; BAR();
        RDH(af, bf, 1, 224);                 MFH(af, bf);   // t=7
    }
#undef RDH
#undef MFH

    // ---------------- phase 3: BN + ReLU + layer-2 -> out ----------------
    __syncthreads();                 // all GEMM LDS reads done
    float* lw   = (float*)lA;        // [10][256] w2 + [10] b2
    float* lred = lw + 2816;         // [4 wc][2 jj][16 l15][10 o]
    for (int t = tid; t < 2560; t += 512) lw[t] = w2[t];
    if (tid < 10) lw[2560 + tid] = b2v[tid];
    __syncthreads();

    float p[2][10];
#pragma unroll
    for (int jj = 0; jj < 2; ++jj)
#pragma unroll
        for (int o = 0; o < 10; ++o) p[jj][o] = 0.f;

#pragma unroll
    for (int i = 0; i < 8; ++i) {
        const int co_b = wr * 128 + i * 16 + l16 * 4;
        float sc[4], sh[4];
#pragma unroll
        for (int r = 0; r < 4; ++r) {
            sc[r] = g[co_b + r] * rsqrtf(vv[co_b + r] + EPS);
            sh[r] = bb[co_b + r] - mm_[co_b + r] * sc[r];
        }
        float w4[10][4];
#pragma unroll
        for (int o = 0; o < 10; ++o) {
            f32x4 wv = *reinterpret_cast<const f32x4*>(&lw[o * 256 + co_b]);
#pragma unroll
            for (int r = 0; r < 4; ++r) w4[o][r] = wv[r];
        }
#pragma unroll
        for (int jj = 0; jj < 2; ++jj) {
            float hv[4];
#pragma unroll
            for (int r = 0; r < 4; ++r)
                hv[r] = fmaxf(fmaf(acc[i][jj][r], sc[r], sh[r]), 0.f);
#pragma unroll
            for (int o = 0; o < 10; ++o)
#pragma unroll
                for (int r = 0; r < 4; ++r)
                    p[jj][o] = fmaf(hv[r], w4[o][r], p[jj][o]);
        }
    }

#pragma unroll
    for (int jj = 0; jj < 2; ++jj)
#pragma unroll
        for (int o = 0; o < 10; ++o) {
            float v = p[jj][o];
            v += __shfl_xor(v, 16, 64);
            v += __shfl_xor(v, 32, 64);
            p[jj][o] = v;
        }

    if (wr == 0 && l16 == 0) {
#pragma unroll
        for (int jj = 0; jj < 2; ++jj)
#pragma unroll
            for (int o = 0; o < 10; ++o)
                lred[((wc * 2 + jj) * 16 + l15) * 10 + o] = p[jj][o];
    }
    __syncthreads();
    if (wr == 1) {
#pragma unroll
        for (int jj = 0; jj < 2; ++jj) {
            const int n = wc * 32 + jj * 16 + l15;
            if (n < 125) {
                const int py = py0 + n / 25, pxc = n % 25;
#pragma unroll
                for (int t = 0; t < 3; ++t) {
                    const int o = l16 + 4 * t;
                    if (o < 10) {
                        float v = p[jj][o]
                                + lred[((wc * 2 + jj) * 16 + l15) * 10 + o]
                                + lw[2560 + o];
                        out[(((size_t)b * 10 + o) * 25 + py) * 25 + pxc] = v;
                    }
                }
            }
        }
    }
}

extern "C" void kernel_launch(void* const* d_in, const int* in_sizes, int n_in,
                              void* d_out, int out_size, void* d_ws, size_t ws_size,
                              hipStream_t stream) {
    const float* kernel = (const float*)d_in[0];   // [128,256,7,7]
    const float* search = (const float*)d_in[1];   // [128,256,31,31]
    const float* w_ck   = (const float*)d_in[2];
    const float* g1 = (const float*)d_in[3];
    const float* b1 = (const float*)d_in[4];
    const float* m1 = (const float*)d_in[5];
    const float* v1 = (const float*)d_in[6];
    const float* w_cs   = (const float*)d_in[7];
    const float* g2 = (const float*)d_in[8];
    const float* b2 = (const float*)d_in[9];
    const float* m2 = (const float*)d_in[10];
    const float* v2 = (const float*)d_in[11];
    const float* w_h1   = (const float*)d_in[12];
    const float* g3 = (const float*)d_in[13];
    const float* b3 = (const float*)d_in[14];
    const float* m3 = (const float*)d_in[15];
    const float* v3 = (const float*)d_in[16];
    const float* w_h2   = (const float*)d_in[17];
    const float* b_h2   = (const float*)d_in[18];

    float* out = (float*)d_out;

    __hip_bfloat16* ws = (__hip_bfloat16*)d_ws;
    __hip_bfloat16* y1    = ws;
    __hip_bfloat16* y2    = ws + (size_t)819200;
    __hip_bfloat16* wt_ck = ws + (size_t)28377088;
    __hip_bfloat16* wt_cs = ws + (size_t)28966912;
    __hip_bfloat16* wh1   = ws + (size_t)29556736;
    __hip_bfloat16* xt_k  = ws + (size_t)29622272;
    __hip_bfloat16* xt_s  = ws + (size_t)31227904;

    (void)in_sizes; (void)n_in; (void)out_size; (void)ws_size;

    // 1) merged pre-passes (wt transposes, w_h1 cast, NHWC converts)
    prepass<<<4992, 256, 0, stream>>>(w_ck, wt_ck, w_cs, wt_cs, w_h1, wh1,
                                      kernel, xt_k, search, xt_s);

    // 2) both convs in one dispatch: search (421 tiles) + kernel branch (13)
    conv_both<<<434, 512, 0, stream>>>(xt_s, wt_cs, g2, b2, m2, v2, y2,
                                       xt_k, wt_ck, g1, b1, m1, v1, y1);

    // 3) fused xcorr + head (layer1 MFMA + BN + ReLU + layer2) -> out
    xcorr_head<<<dim3(5, 128), 512, 0, stream>>>(
        y2, y1, wh1, g3, b3, m3, v3, w_h2, b_h2, out);
}